// Round 6
// baseline (4649.949 us; speedup 1.0000x reference)
//
#include <hip/hip_runtime.h>
#include <hip/hip_cooperative_groups.h>
#include <math.h>

namespace cg = cooperative_groups;

#define DI __device__ __forceinline__

DI float sigm(float x){ return 1.0f/(1.0f+expf(-x)); }
DI float lrelu(float x){ return x > 0.f ? x : 0.01f*x; }

template<int ACT>
DI float act_apply(float v){
    if (ACT == 1) return tanhf(v);
    if (ACT == 2) return lrelu(v);
    return v;
}

// ---------------- encoder conv: stride 2, 4x4, tanh ----------------
template<int CIN, int COUT>
__global__ __launch_bounds__(256)
void conv_enc_kernel(const float* __restrict__ in, const float* __restrict__ w,
                     const float* __restrict__ bias, float* __restrict__ out,
                     int N, int H, int OH)
{
    int idx = blockIdx.x*256 + threadIdx.x;
    int total = N*COUT*OH*OH;
    if (idx >= total) return;
    int ox = idx % OH; int t = idx / OH;
    int oy = t % OH;   t /= OH;
    int o  = t % COUT; int n = t / COUT;
    float acc = bias[o];
    const float* wp = w + o*CIN*16;
    const float* ip = in + ((size_t)n*CIN)*H*H + (oy*2)*H + ox*2;
    for (int c = 0; c < CIN; ++c) {
        const float* ipc = ip + c*H*H;
        const float* wpc = wp + c*16;
        #pragma unroll
        for (int ky = 0; ky < 4; ++ky)
            #pragma unroll
            for (int kx = 0; kx < 4; ++kx)
                acc = fmaf(ipc[ky*H + kx], wpc[ky*4 + kx], acc);
    }
    out[idx] = tanhf(acc);
}

// ---------------- tiled GEMM: C = act(A @ op(B) + bias) ----------------
template<int BM,int BN,int BK,bool BT,int ACT>
__global__ __launch_bounds__((BM/4)*(BN/4))
void gemm_kernel(const float* __restrict__ A, const float* __restrict__ Bm,
                 const float* __restrict__ bias, float* __restrict__ C,
                 int M, int N, int Kfull, int klen, int ldc, int bias_div,
                 long partStride)
{
    constexpr int TM = 4, TN = 4;
    constexpr int THREADS = (BM/TM)*(BN/TN);
    constexpr int LDA = BM + 4, LDB = BN + 4;
    __shared__ __align__(16) float As[BK][LDA];
    __shared__ __align__(16) float Bs[BK][LDB];
    int tid = threadIdx.x;
    int m0 = blockIdx.y * BM, n0 = blockIdx.x * BN;
    int koff = blockIdx.z * klen;
    C += (long)blockIdx.z * partStride;
    constexpr int NTX = BN/TN;
    int tx = tid % NTX, ty = tid / NTX;
    float acc[4][4];
    #pragma unroll
    for (int i=0;i<4;++i)
        #pragma unroll
        for (int j=0;j<4;++j) acc[i][j] = 0.f;

    for (int k0 = 0; k0 < klen; k0 += BK) {
        for (int e = tid; e < BM*BK; e += THREADS) {
            int k = e % BK, m = e / BK;
            As[k][m] = (m0+m < M) ? A[(size_t)(m0+m)*Kfull + koff + k0 + k] : 0.f;
        }
        if (BT) {
            for (int e = tid; e < BN*BK; e += THREADS) {
                int k = e % BK, n = e / BK;
                Bs[k][n] = (n0+n < N) ? Bm[(size_t)(n0+n)*Kfull + koff + k0 + k] : 0.f;
            }
        } else {
            for (int e = tid; e < BN*BK; e += THREADS) {
                int n = e % BN, k = e / BN;
                Bs[k][n] = (n0+n < N) ? Bm[(size_t)(koff + k0 + k)*N + n0+n] : 0.f;
            }
        }
        __syncthreads();
        #pragma unroll 8
        for (int k = 0; k < BK; ++k) {
            float4 a4 = *reinterpret_cast<const float4*>(&As[k][ty*4]);
            float4 b4 = *reinterpret_cast<const float4*>(&Bs[k][tx*4]);
            float av[4] = {a4.x, a4.y, a4.z, a4.w};
            float bv[4] = {b4.x, b4.y, b4.z, b4.w};
            #pragma unroll
            for (int i=0;i<4;++i)
                #pragma unroll
                for (int j=0;j<4;++j)
                    acc[i][j] = fmaf(av[i], bv[j], acc[i][j]);
        }
        __syncthreads();
    }
    #pragma unroll
    for (int i=0;i<4;++i) {
        int m = m0 + ty*4 + i;
        if (m >= M) continue;
        #pragma unroll
        for (int j=0;j<4;++j) {
            int n = n0 + tx*4 + j;
            if (n >= N) continue;
            float v = acc[i][j] + (bias ? bias[n / bias_div] : 0.f);
            C[(size_t)m*ldc + n] = act_apply<ACT>(v);
        }
    }
}

// ---------------- small helpers ----------------
__global__ __launch_bounds__(64)
void concat_action_kernel(const float* __restrict__ action, float* __restrict__ z)
{
    int i = blockIdx.x*64 + threadIdx.x;
    if (i < 50*30) { int b = i/30, k = i%30; z[b*512 + 482 + k] = action[i]; }
}

__global__ __launch_bounds__(64)
void reward_kernel(const float* __restrict__ z, const float* __restrict__ w,
                   const float* __restrict__ b, float* __restrict__ out)
{
    int bi = threadIdx.x;
    if (bi < 50) {
        float acc = b[0];
        for (int k = 0; k < 512; ++k) acc = fmaf(z[bi*512 + k], w[k], acc);
        out[bi] = acc;
    }
}

// transpose [50][1024] -> [1024][64] (zero-padded cols 50..63)
__global__ __launch_bounds__(256)
void transpose_bt_kernel(const float* __restrict__ in, float* __restrict__ out)
{
    int idx = blockIdx.x*256 + threadIdx.x;
    if (idx >= 1024*64) return;
    int j = idx >> 6, b = idx & 63;
    out[idx] = (b < 50) ? in[(size_t)b*1024 + j] : 0.f;
}

// ---------------- cooperative fused LSTM: all 17 steps in one kernel --------
// 256 blocks x 256 threads. Block blk owns h-cols {4blk..4blk+3} and their 4
// gate rows (i,f,g,o at +1024q). wsum = w_ih+w_hh staged once in LDS (64 KB).
// h passed between steps via ping-pong hT[2][1024][64]; c stays in LDS.
// One grid.sync per step (ping-pong removes the read/write overlap).
__global__ __launch_bounds__(256)
void lstm_coop_kernel(const float* __restrict__ fc2oT, const float* __restrict__ h0T,
                      const float* __restrict__ c0,
                      const float* __restrict__ w_ih, const float* __restrict__ w_hh,
                      const float* __restrict__ b_ih, const float* __restrict__ b_hh,
                      float* __restrict__ hTbuf, float* __restrict__ outs)
{
    constexpr int LDW = 1025;
    __shared__ float wlds[16*LDW];
    __shared__ float gbuf[16][64];
    __shared__ float cst[4][52];
    __shared__ float ldsb[16];
    const int blk = blockIdx.x;
    const int tid = threadIdx.x;

    // stage wsum rows for the 16 owned gate rows; bias; c0
    for (int e = tid; e < 16*1024; e += 256) {
        int jcol = e >> 10, k = e & 1023;
        int row = 4*blk + (jcol & 3) + 1024*(jcol >> 2);
        wlds[jcol*LDW + k] = w_ih[(size_t)row*1024 + k] + w_hh[(size_t)row*1024 + k];
    }
    if (tid < 16) {
        int row = 4*blk + (tid & 3) + 1024*(tid >> 2);
        ldsb[tid] = b_ih[row] + b_hh[row];
    }
    if (tid < 200) {
        int ci = tid & 3, b = tid >> 2;
        cst[ci][b] = c0[(size_t)b*1024 + 4*blk + ci];
    }

    cg::grid_group grid = cg::this_grid();

    const int jp = tid >> 5;     // 0..7
    const int bg = tid & 31;     // 0..31
    const int jc0 = jp, jc1 = jp + 8;
    const int row0 = 4*blk + (jc0 & 3) + 1024*(jc0 >> 2);
    const int row1 = 4*blk + (jc1 & 3) + 1024*(jc1 >> 2);

    for (int t = 0; t < 17; ++t) {
        float a00 = 0.f, a01 = 0.f, a10 = 0.f, a11 = 0.f;
        if (t == 0) {
            const float* wa = w_ih + (size_t)row0*1024;
            const float* wb = w_ih + (size_t)row1*1024;
            #pragma unroll 4
            for (int k = 0; k < 1024; ++k) {
                float x0 = fc2oT[k*64 + bg];
                float x1 = fc2oT[k*64 + bg + 32];
                float w0 = wa[k], w1 = wb[k];
                a00 = fmaf(w0, x0, a00); a01 = fmaf(w0, x1, a01);
                a10 = fmaf(w1, x0, a10); a11 = fmaf(w1, x1, a11);
            }
            wa = w_hh + (size_t)row0*1024;
            wb = w_hh + (size_t)row1*1024;
            #pragma unroll 4
            for (int k = 0; k < 1024; ++k) {
                float x0 = h0T[k*64 + bg];
                float x1 = h0T[k*64 + bg + 32];
                float w0 = wa[k], w1 = wb[k];
                a00 = fmaf(w0, x0, a00); a01 = fmaf(w0, x1, a01);
                a10 = fmaf(w1, x0, a10); a11 = fmaf(w1, x1, a11);
            }
        } else {
            const float* hTr = hTbuf + (size_t)(t & 1)*65536;
            const float* wa = wlds + jc0*LDW;
            const float* wb = wlds + jc1*LDW;
            #pragma unroll 4
            for (int k = 0; k < 1024; ++k) {
                float x0 = hTr[k*64 + bg];
                float x1 = hTr[k*64 + bg + 32];
                float w0 = wa[k], w1 = wb[k];
                a00 = fmaf(w0, x0, a00); a01 = fmaf(w0, x1, a01);
                a10 = fmaf(w1, x0, a10); a11 = fmaf(w1, x1, a11);
            }
        }
        gbuf[jc0][bg] = a00; gbuf[jc0][bg+32] = a01;
        gbuf[jc1][bg] = a10; gbuf[jc1][bg+32] = a11;
        __syncthreads();
        if (tid < 200) {
            int ci = tid & 3, b = tid >> 2;
            float gi = gbuf[ci][b]      + ldsb[ci];
            float gf = gbuf[4+ci][b]    + ldsb[4+ci];
            float gg = gbuf[8+ci][b]    + ldsb[8+ci];
            float go = gbuf[12+ci][b]   + ldsb[12+ci];
            float c = sigm(gf)*cst[ci][b] + sigm(gi)*tanhf(gg);
            float h = sigm(go)*tanhf(c);
            cst[ci][b] = c;
            int col = 4*blk + ci;
            float* hTw = hTbuf + (size_t)((t + 1) & 1)*65536;
            hTw[(size_t)col*64 + b] = h;
            outs[(size_t)t*51200 + (size_t)b*1024 + col] = h;
        }
        if (t < 16) { __threadfence(); grid.sync(); }
        else        { __syncthreads(); }
    }
}

// ---------------- weight prep for parity-decomposed deconv ----------------
__global__ __launch_bounds__(256)
void wprep_kernel(const float* __restrict__ w, float* __restrict__ wp,
                  int CIN, int COUT, int KS)
{
    int idx = blockIdx.x*256 + threadIdx.x;
    int total = 4*CIN*COUT*12;
    if (idx >= total) return;
    int slot = idx % 12; int rem = idx / 12;
    int o = rem % COUT; rem /= COUT;
    int c = rem % CIN;  int pp = rem / CIN;
    int py = pp >> 1, px = pp & 1;
    int j = slot >> 2, i = slot & 3;
    int ky = py + 2*j, kx = px + 2*i;
    float v = 0.f;
    if (i < 3 && ky < KS && kx < KS)
        v = w[(((size_t)c*COUT + o)*KS + ky)*KS + kx];
    wp[idx] = v;
}

// ---------------- parity-merged transposed conv, v-split blocks -------------
template<int CIN,int COUT,int HIN,int HOUT,int ACT,int VSPLIT,int ROWP,int TWU,
         int VPER,int TB,int MWAVES,int ISTR,int OSTR>
__global__ __launch_bounds__(256, MWAVES)
void deconv4_kernel(const float* __restrict__ in, const float* __restrict__ wp,
                    const float* __restrict__ bias, float* __restrict__ out)
{
    constexpr int NV = (HOUT + 1) / 2;
    constexpr int NVSEG = (NV + VSPLIT - 1) / VSPLIT;
    constexpr int NVB = (NVSEG + VPER - 1) / VPER;
    constexpr int ROWS_MAX = (NVSEG + 2 < HIN) ? (NVSEG + 2) : HIN;
    constexpr int NR4 = (TWU + 2 + 3) / 4;
    constexpr int RLEN = (TWU == 1) ? 4 : NR4*4;
    static_assert(NVB * COUT * TB <= 256, "tasks must fit one per thread");
    __shared__ __align__(16) float slab[CIN*ROWS_MAX*ROWP];

    int n   = blockIdx.x / VSPLIT;
    int seg = blockIdx.x % VSPLIT;
    int v0 = seg * NVSEG;
    int v1 = (v0 + NVSEG < NV) ? v0 + NVSEG : NV;
    int r0 = (v0 - 2 > 0) ? v0 - 2 : 0;
    int r1m = (v1 - 1 < HIN - 1) ? v1 - 1 : HIN - 1;
    int nrows = r1m - r0 + 1;
    int tid = threadIdx.x;
    const float* inb = in + (size_t)n*CIN*HIN*ISTR;
    const size_t PPSTR = (size_t)CIN*COUT*12;

    for (int e = tid; e < CIN*ROWS_MAX; e += 256) {
        int c = e / ROWS_MAX, ri = e % ROWS_MAX;
        if (ri < nrows) {
            const float* src = inb + ((size_t)c*HIN + r0 + ri)*ISTR;
            float* dst = slab + (c*ROWS_MAX + ri)*ROWP;
            dst[0] = 0.f; dst[1] = 0.f;
            #pragma unroll
            for (int x2 = HIN+2; x2 < ROWP; ++x2) dst[x2] = 0.f;
            for (int x2 = 0; x2 < HIN; ++x2) dst[2+x2] = src[x2];
        }
    }
    __syncthreads();

    int task = tid;
    int vi = task % NVB; int rem = task / NVB;
    int o = rem % COUT;  int tb = rem / COUT;
    int u0 = tb * TWU;
    bool anyv = false;
    int vg[VPER];
    #pragma unroll
    for (int q = 0; q < VPER; ++q) {
        vg[q] = v0 + vi + q*NVB;
        if (vg[q] < v1) anyv = true;
    }
    if (tb >= TB) anyv = false;

    float acc[VPER][2][2][TWU];
    #pragma unroll
    for (int q=0;q<VPER;++q)
        #pragma unroll
        for (int a=0;a<2;++a)
            #pragma unroll
            for (int b=0;b<2;++b)
                #pragma unroll
                for (int t=0;t<TWU;++t) acc[q][a][b][t] = 0.f;

    if (anyv) {
        const float* wb0 = wp + (size_t)o*12;
        for (int c = 0; c < CIN; ++c) {
            const float* wbase = wb0 + (size_t)c*COUT*12;
            const float* sc = slab + c*(ROWS_MAX*ROWP);
            #pragma unroll
            for (int jj = 0; jj < 3; ++jj) {
                float r[VPER][RLEN];
                #pragma unroll
                for (int q = 0; q < VPER; ++q) {
                    int iy = vg[q] - jj;
                    if (iy >= 0 && iy < HIN) {
                        const float* srow = sc + (iy - r0)*ROWP + u0;
                        if constexpr (TWU == 1) {
                            r[q][0] = srow[0]; r[q][1] = srow[1]; r[q][2] = srow[2];
                        } else {
                            #pragma unroll
                            for (int p4 = 0; p4 < NR4; ++p4) {
                                float4 f = *reinterpret_cast<const float4*>(srow + p4*4);
                                r[q][p4*4]=f.x; r[q][p4*4+1]=f.y; r[q][p4*4+2]=f.z; r[q][p4*4+3]=f.w;
                            }
                        }
                    } else {
                        #pragma unroll
                        for (int p4 = 0; p4 < RLEN; ++p4) r[q][p4] = 0.f;
                    }
                }
                #pragma unroll
                for (int pp = 0; pp < 4; ++pp) {
                    float4 w4 = *reinterpret_cast<const float4*>(wbase + pp*PPSTR + jj*4);
                    int py = pp >> 1, px = pp & 1;
                    #pragma unroll
                    for (int q = 0; q < VPER; ++q)
                        #pragma unroll
                        for (int t = 0; t < TWU; ++t)
                            acc[q][py][px][t] =
                                fmaf(w4.x, r[q][t+2],
                                fmaf(w4.y, r[q][t+1],
                                fmaf(w4.z, r[q][t], acc[q][py][px][t])));
                }
            }
        }
        float bv = bias[o];
        #pragma unroll
        for (int q = 0; q < VPER; ++q) {
            if (vg[q] >= v1) continue;
            #pragma unroll
            for (int py = 0; py < 2; ++py) {
                int y = py + 2*vg[q];
                if (y >= HOUT) continue;
                float* ob = out + (((size_t)n*COUT + o)*HOUT + y)*OSTR;
                #pragma unroll
                for (int t = 0; t < TWU; ++t) {
                    int x0 = 2*(u0+t);
                    if (x0 + 1 < HOUT) {
                        float2 qv;
                        qv.x = act_apply<ACT>(acc[q][py][0][t] + bv);
                        qv.y = act_apply<ACT>(acc[q][py][1][t] + bv);
                        *reinterpret_cast<float2*>(ob + x0) = qv;
                    } else if (x0 < HOUT) {
                        ob[x0] = act_apply<ACT>(acc[q][py][0][t] + bv);
                    }
                }
            }
        }
    }
}

// ---------------- launch ----------------
extern "C" void kernel_launch(void* const* d_in, const int* in_sizes, int n_in,
                              void* d_out, int out_size, void* d_ws, size_t ws_size,
                              hipStream_t stream)
{
    const float* x       = (const float*)d_in[0];
    const float* action  = (const float*)d_in[1];
    const float* h0      = (const float*)d_in[2];
    const float* c0      = (const float*)d_in[3];
    const float* conv1_w = (const float*)d_in[4];  const float* conv1_b = (const float*)d_in[5];
    const float* conv2_w = (const float*)d_in[6];  const float* conv2_b = (const float*)d_in[7];
    const float* conv3_w = (const float*)d_in[8];  const float* conv3_b = (const float*)d_in[9];
    const float* conv4_w = (const float*)d_in[10]; const float* conv4_b = (const float*)d_in[11];
    const float* fc1_w   = (const float*)d_in[12]; const float* fc1_b   = (const float*)d_in[13];
    const float* fc2_w   = (const float*)d_in[14]; const float* fc2_b   = (const float*)d_in[15];
    const float* w_ih    = (const float*)d_in[16]; const float* w_hh    = (const float*)d_in[17];
    const float* b_ih    = (const float*)d_in[18]; const float* b_hh    = (const float*)d_in[19];
    const float* fcsd_w  = (const float*)d_in[20]; const float* fcsd_b  = (const float*)d_in[21];
    const float* d1_w    = (const float*)d_in[22]; const float* d1_b    = (const float*)d_in[23];
    const float* d2_w    = (const float*)d_in[24]; const float* d2_b    = (const float*)d_in[25];
    const float* d3_w    = (const float*)d_in[26]; const float* d3_b    = (const float*)d_in[27];
    const float* d4_w    = (const float*)d_in[28]; const float* d4_b    = (const float*)d_in[29];
    const float* fc5_w   = (const float*)d_in[30]; const float* fc5_b   = (const float*)d_in[31];
    float* out = (float*)d_out;
    float* ws  = (float*)d_ws;

    // workspace layout (floats), unpadded y2/y3 (round-4 best config)
    float* a1    = ws;                  // 1,537,600  [50,32,31,31]
    float* a2    = a1 + 1537600;        //   627,200  [50,64,14,14]
    float* a3    = a2 + 627200;         //   230,400  [50,128,6,6]
    float* flat  = a3 + 230400;         //    51,200  [50,1024]
    float* z     = flat + 51200;        //    25,600  [50,512]
    float* fc2o  = z + 25600;           //    51,200  [50,1024]
    float* outs  = fc2o + 51200;        //   870,400  [17,50,1024]
    float* hd    = outs + 870400;       //   870,400  [850,1024]
    float* wp2   = hd + 870400;         //   393,216
    float* wp3   = wp2 + 393216;        //    98,304
    float* wp4   = wp3 + 98304;         //     1,536
    float* y1    = wp4 + 1536;          //  2,720,000  [850,128,5,5]
    float* y2    = y1 + 2720000;        //  9,193,600  [850,64,13,13]
    float* y3    = y2 + 9193600;        // 24,480,000  [850,32,30,30]
    float* fc2oT = y3 + 24480000;       //    65,536  [1024][64]
    float* h0T   = fc2oT + 65536;       //    65,536
    float* hTbuf = h0T + 65536;         //   131,072  ping-pong [2][1024][64]

    const int B = 50;

    // deconv weight prep
    wprep_kernel<<<(4*128*64*12+255)/256, 256, 0, stream>>>(d2_w, wp2, 128, 64, 5);
    wprep_kernel<<<(4*64*32*12+255)/256, 256, 0, stream>>>(d3_w, wp3, 64, 32, 6);
    wprep_kernel<<<(4*32*1*12+255)/256, 256, 0, stream>>>(d4_w, wp4, 32, 1, 6);

    // encoder
    conv_enc_kernel<1,32><<<(B*32*31*31+255)/256, 256, 0, stream>>>(x, conv1_w, conv1_b, a1, B, 64, 31);
    conv_enc_kernel<32,64><<<(B*64*14*14+255)/256, 256, 0, stream>>>(a1, conv2_w, conv2_b, a2, B, 31, 14);
    conv_enc_kernel<64,128><<<(B*128*6*6+255)/256, 256, 0, stream>>>(a2, conv3_w, conv3_b, a3, B, 14, 6);
    conv_enc_kernel<128,256><<<(B*256*2*2+255)/256, 256, 0, stream>>>(a3, conv4_w, conv4_b, flat, B, 6, 2);

    // fc1 -> z[:, :482]; action -> z[:, 482:512]; reward head
    {
        dim3 grid((482+63)/64, (B+31)/32, 1);
        gemm_kernel<32,64,32,true,0><<<grid, 128, 0, stream>>>(flat, fc1_w, fc1_b, z, B, 482, 1024, 1024, 512, 1, 0);
    }
    concat_action_kernel<<<(1500+63)/64, 64, 0, stream>>>(action, z);
    reward_kernel<<<1, 64, 0, stream>>>(z, fc5_w, fc5_b, out + (size_t)850*4096);

    // fc2 (leaky relu)
    {
        dim3 grid((1024+63)/64, (B+31)/32, 1);
        gemm_kernel<32,64,32,true,2><<<grid, 128, 0, stream>>>(z, fc2_w, fc2_b, fc2o, B, 1024, 512, 512, 1024, 1, 0);
    }

    // LSTM: transpose inputs, then one cooperative kernel for all 17 steps
    transpose_bt_kernel<<<(65536+255)/256, 256, 0, stream>>>(fc2o, fc2oT);
    transpose_bt_kernel<<<(65536+255)/256, 256, 0, stream>>>(h0, h0T);
    {
        void* kargs[] = { (void*)&fc2oT, (void*)&h0T, (void*)&c0,
                          (void*)&w_ih, (void*)&w_hh, (void*)&b_ih, (void*)&b_hh,
                          (void*)&hTbuf, (void*)&outs };
        hipLaunchCooperativeKernel((const void*)lstm_coop_kernel,
                                   dim3(256), dim3(256), kargs, 0, stream);
    }

    // fcsd: hd = leaky(outs @ fcsd_w^T + fcsd_b)   [850,1024]
    {
        dim3 grid((1024+63)/64, (850+63)/64, 1);
        gemm_kernel<64,64,32,true,2><<<grid, 256, 0, stream>>>(outs, fcsd_w, fcsd_b, hd, 850, 1024, 1024, 1024, 1024, 1, 0);
    }
    // d1: 1x1 spatial input -> pure GEMM [850,1024]x[1024,3200], tanh
    {
        dim3 grid((3200+63)/64, (850+63)/64, 1);
        gemm_kernel<64,64,32,false,1><<<grid, 256, 0, stream>>>(hd, d1_w, d1_b, y1, 850, 3200, 1024, 1024, 3200, 25, 0);
    }

    // d2/d3/d4: round-4 best configs (unpadded strides)
    deconv4_kernel<128,64,5,13,1, 1,12,7,2,1,3, 5,13><<<850, 256, 0, stream>>>(y1, wp2, d2_b, y2);
    deconv4_kernel<64,32,13,30,1, 2,20,15,1,1,3, 13,30><<<1700, 256, 0, stream>>>(y2, wp3, d3_b, y3);
    deconv4_kernel<32,1,30,64,0, 4,36,1,1,32,3, 30,64><<<3400, 256, 0, stream>>>(y3, wp4, d4_b, out);

    (void)in_sizes; (void)n_in; (void)out_size; (void)ws_size;
}

// Round 7
// 4528.742 us; speedup vs baseline: 1.0268x; 1.0268x over previous
//
#include <hip/hip_runtime.h>
#include <hip/hip_cooperative_groups.h>
#include <math.h>

namespace cg = cooperative_groups;

#define DI __device__ __forceinline__

DI float sigm(float x){ return 1.0f/(1.0f+expf(-x)); }
DI float lrelu(float x){ return x > 0.f ? x : 0.01f*x; }

template<int ACT>
DI float act_apply(float v){
    if (ACT == 1) return tanhf(v);
    if (ACT == 2) return lrelu(v);
    return v;
}

// ---------------- encoder conv: stride 2, 4x4, tanh ----------------
template<int CIN, int COUT>
__global__ __launch_bounds__(256)
void conv_enc_kernel(const float* __restrict__ in, const float* __restrict__ w,
                     const float* __restrict__ bias, float* __restrict__ out,
                     int N, int H, int OH)
{
    int idx = blockIdx.x*256 + threadIdx.x;
    int total = N*COUT*OH*OH;
    if (idx >= total) return;
    int ox = idx % OH; int t = idx / OH;
    int oy = t % OH;   t /= OH;
    int o  = t % COUT; int n = t / COUT;
    float acc = bias[o];
    const float* wp = w + o*CIN*16;
    const float* ip = in + ((size_t)n*CIN)*H*H + (oy*2)*H + ox*2;
    for (int c = 0; c < CIN; ++c) {
        const float* ipc = ip + c*H*H;
        const float* wpc = wp + c*16;
        #pragma unroll
        for (int ky = 0; ky < 4; ++ky)
            #pragma unroll
            for (int kx = 0; kx < 4; ++kx)
                acc = fmaf(ipc[ky*H + kx], wpc[ky*4 + kx], acc);
    }
    out[idx] = tanhf(acc);
}

// ---------------- tiled GEMM: C = act(A @ op(B) + bias) ----------------
template<int BM,int BN,int BK,bool BT,int ACT>
__global__ __launch_bounds__((BM/4)*(BN/4))
void gemm_kernel(const float* __restrict__ A, const float* __restrict__ Bm,
                 const float* __restrict__ bias, float* __restrict__ C,
                 int M, int N, int Kfull, int klen, int ldc, int bias_div,
                 long partStride)
{
    constexpr int TM = 4, TN = 4;
    constexpr int THREADS = (BM/TM)*(BN/TN);
    constexpr int LDA = BM + 4, LDB = BN + 4;
    __shared__ __align__(16) float As[BK][LDA];
    __shared__ __align__(16) float Bs[BK][LDB];
    int tid = threadIdx.x;
    int m0 = blockIdx.y * BM, n0 = blockIdx.x * BN;
    int koff = blockIdx.z * klen;
    C += (long)blockIdx.z * partStride;
    constexpr int NTX = BN/TN;
    int tx = tid % NTX, ty = tid / NTX;
    float acc[4][4];
    #pragma unroll
    for (int i=0;i<4;++i)
        #pragma unroll
        for (int j=0;j<4;++j) acc[i][j] = 0.f;

    for (int k0 = 0; k0 < klen; k0 += BK) {
        for (int e = tid; e < BM*BK; e += THREADS) {
            int k = e % BK, m = e / BK;
            As[k][m] = (m0+m < M) ? A[(size_t)(m0+m)*Kfull + koff + k0 + k] : 0.f;
        }
        if (BT) {
            for (int e = tid; e < BN*BK; e += THREADS) {
                int k = e % BK, n = e / BK;
                Bs[k][n] = (n0+n < N) ? Bm[(size_t)(n0+n)*Kfull + koff + k0 + k] : 0.f;
            }
        } else {
            for (int e = tid; e < BN*BK; e += THREADS) {
                int n = e % BN, k = e / BN;
                Bs[k][n] = (n0+n < N) ? Bm[(size_t)(koff + k0 + k)*N + n0+n] : 0.f;
            }
        }
        __syncthreads();
        #pragma unroll 8
        for (int k = 0; k < BK; ++k) {
            float4 a4 = *reinterpret_cast<const float4*>(&As[k][ty*4]);
            float4 b4 = *reinterpret_cast<const float4*>(&Bs[k][tx*4]);
            float av[4] = {a4.x, a4.y, a4.z, a4.w};
            float bv[4] = {b4.x, b4.y, b4.z, b4.w};
            #pragma unroll
            for (int i=0;i<4;++i)
                #pragma unroll
                for (int j=0;j<4;++j)
                    acc[i][j] = fmaf(av[i], bv[j], acc[i][j]);
        }
        __syncthreads();
    }
    #pragma unroll
    for (int i=0;i<4;++i) {
        int m = m0 + ty*4 + i;
        if (m >= M) continue;
        #pragma unroll
        for (int j=0;j<4;++j) {
            int n = n0 + tx*4 + j;
            if (n >= N) continue;
            float v = acc[i][j] + (bias ? bias[n / bias_div] : 0.f);
            C[(size_t)m*ldc + n] = act_apply<ACT>(v);
        }
    }
}

// ---------------- small helpers ----------------
__global__ __launch_bounds__(64)
void concat_action_kernel(const float* __restrict__ action, float* __restrict__ z)
{
    int i = blockIdx.x*64 + threadIdx.x;
    if (i < 50*30) { int b = i/30, k = i%30; z[b*512 + 482 + k] = action[i]; }
}

__global__ __launch_bounds__(64)
void reward_kernel(const float* __restrict__ z, const float* __restrict__ w,
                   const float* __restrict__ b, float* __restrict__ out)
{
    int bi = threadIdx.x;
    if (bi < 50) {
        float acc = b[0];
        for (int k = 0; k < 512; ++k) acc = fmaf(z[bi*512 + k], w[k], acc);
        out[bi] = acc;
    }
}

// transpose [50][1024] -> [1024][64] (zero-padded cols 50..63)
__global__ __launch_bounds__(256)
void transpose_bt_kernel(const float* __restrict__ in, float* __restrict__ out)
{
    int idx = blockIdx.x*256 + threadIdx.x;
    if (idx >= 1024*64) return;
    int j = idx >> 6, b = idx & 63;
    out[idx] = (b < 50) ? in[(size_t)b*1024 + j] : 0.f;
}

// tiled transpose of [4096][1024] -> out[(kOff+k)*4096 + r]; optional add of b2
__global__ __launch_bounds__(256)
void transpose_w_kernel(const float* __restrict__ a, const float* __restrict__ b2,
                        float* __restrict__ out, int kOff)
{
    __shared__ float tile[32][33];
    int k0 = blockIdx.x * 32;
    int r0 = blockIdx.y * 32;
    int tx = threadIdx.x & 31, ty = threadIdx.x >> 5;   // ty 0..7
    #pragma unroll
    for (int i = 0; i < 32; i += 8) {
        size_t src = (size_t)(r0 + ty + i)*1024 + k0 + tx;
        float v = a[src];
        if (b2) v += b2[src];
        tile[ty + i][tx] = v;
    }
    __syncthreads();
    #pragma unroll
    for (int i = 0; i < 32; i += 8) {
        int k = k0 + ty + i, r = r0 + tx;
        out[(size_t)(kOff + k)*4096 + r] = tile[tx][ty + i];
    }
}

// ---------------- cooperative fused LSTM v2: LDS-free inner loop ------------
// 256 blocks x 512 threads (8 waves). Block owns 16 gate-rows
// {g*1024 + 4blk + i} and all 64 batch cols. Wave ks = k-slice; lane (rg,cg)
// computes a 4row x 4col register tile: per k, 1 float4 w-load (wsumT, L2-hot)
// + 1 float4 x-load (hT, L2) + 16 FMAs. 8 partials reduced in LDS per step.
__global__ __launch_bounds__(512)
void lstm_coop2_kernel(const float* __restrict__ xx0T, const float* __restrict__ wcatT,
                       const float* __restrict__ wsumT, const float* __restrict__ c0,
                       const float* __restrict__ b_ih, const float* __restrict__ b_hh,
                       float* __restrict__ hTbuf, float* __restrict__ outs)
{
    __shared__ float gpart[8][16][64];
    __shared__ float cst[4][50];
    __shared__ float ldsb[16];
    const int blk = blockIdx.x;
    const int tid = threadIdx.x;
    const int ks  = tid >> 6;        // 0..7 (wave)
    const int lane = tid & 63;
    const int rg  = lane >> 4;       // gate group 0..3
    const int cg  = lane & 15;       // col group 0..15
    const int wcol = 4*blk + rg*1024;

    if (tid < 16) {
        int row = 4*blk + (tid & 3) + 1024*(tid >> 2);
        ldsb[tid] = b_ih[row] + b_hh[row];
    }
    if (tid < 200) {
        int ci = tid & 3, b = tid >> 2;
        cst[ci][b] = c0[(size_t)b*1024 + 4*blk + ci];
    }
    cg::grid_group grid = cg::this_grid();

    for (int t = 0; t < 17; ++t) {
        const float* xb; const float* wb; int klen;
        if (t == 0) { xb = xx0T; wb = wcatT; klen = 256; }
        else        { xb = hTbuf + (size_t)(t & 1)*65536; wb = wsumT; klen = 128; }
        const float* xptr = xb + (size_t)(ks*klen)*64 + cg*4;
        const float* wptr = wb + (size_t)(ks*klen)*4096 + wcol;
        float acc[4][4];
        #pragma unroll
        for (int i=0;i<4;++i)
            #pragma unroll
            for (int j=0;j<4;++j) acc[i][j] = 0.f;
        #pragma unroll 4
        for (int kk = 0; kk < klen; ++kk) {
            float4 w4 = *reinterpret_cast<const float4*>(wptr);
            float4 x4 = *reinterpret_cast<const float4*>(xptr);
            wptr += 4096; xptr += 64;
            float wv[4] = {w4.x, w4.y, w4.z, w4.w};
            float xv[4] = {x4.x, x4.y, x4.z, x4.w};
            #pragma unroll
            for (int i=0;i<4;++i)
                #pragma unroll
                for (int j=0;j<4;++j)
                    acc[i][j] = fmaf(wv[i], xv[j], acc[i][j]);
        }
        __syncthreads();   // prev-step reduce finished before gpart overwrite
        #pragma unroll
        for (int i = 0; i < 4; ++i) {
            float4 v = make_float4(acc[i][0], acc[i][1], acc[i][2], acc[i][3]);
            *reinterpret_cast<float4*>(&gpart[ks][rg*4 + i][cg*4]) = v;
        }
        __syncthreads();
        if (tid < 200) {
            int ci = tid & 3, b = tid >> 2;
            float s0 = ldsb[ci], s1 = ldsb[4+ci], s2 = ldsb[8+ci], s3 = ldsb[12+ci];
            #pragma unroll
            for (int p = 0; p < 8; ++p) {
                s0 += gpart[p][ci][b];    s1 += gpart[p][4+ci][b];
                s2 += gpart[p][8+ci][b];  s3 += gpart[p][12+ci][b];
            }
            float c = sigm(s1)*cst[ci][b] + sigm(s0)*tanhf(s2);
            float h = sigm(s3)*tanhf(c);
            cst[ci][b] = c;
            int col = 4*blk + ci;
            hTbuf[(size_t)((t + 1) & 1)*65536 + (size_t)col*64 + b] = h;
            outs[(size_t)t*51200 + (size_t)b*1024 + col] = h;
        }
        if (t < 16) { __threadfence(); grid.sync(); }
    }
}

// ---------------- weight prep for parity-decomposed deconv ----------------
__global__ __launch_bounds__(256)
void wprep_kernel(const float* __restrict__ w, float* __restrict__ wp,
                  int CIN, int COUT, int KS)
{
    int idx = blockIdx.x*256 + threadIdx.x;
    int total = 4*CIN*COUT*12;
    if (idx >= total) return;
    int slot = idx % 12; int rem = idx / 12;
    int o = rem % COUT; rem /= COUT;
    int c = rem % CIN;  int pp = rem / CIN;
    int py = pp >> 1, px = pp & 1;
    int j = slot >> 2, i = slot & 3;
    int ky = py + 2*j, kx = px + 2*i;
    float v = 0.f;
    if (i < 3 && ky < KS && kx < KS)
        v = w[(((size_t)c*COUT + o)*KS + ky)*KS + kx];
    wp[idx] = v;
}

// ---------------- parity-merged transposed conv, v-split blocks -------------
template<int CIN,int COUT,int HIN,int HOUT,int ACT,int VSPLIT,int ROWP,int TWU,
         int VPER,int TB,int MWAVES,int ISTR,int OSTR>
__global__ __launch_bounds__(256, MWAVES)
void deconv4_kernel(const float* __restrict__ in, const float* __restrict__ wp,
                    const float* __restrict__ bias, float* __restrict__ out)
{
    constexpr int NV = (HOUT + 1) / 2;
    constexpr int NVSEG = (NV + VSPLIT - 1) / VSPLIT;
    constexpr int NVB = (NVSEG + VPER - 1) / VPER;
    constexpr int ROWS_MAX = (NVSEG + 2 < HIN) ? (NVSEG + 2) : HIN;
    constexpr int NR4 = (TWU + 2 + 3) / 4;
    constexpr int RLEN = (TWU == 1) ? 4 : NR4*4;
    static_assert(NVB * COUT * TB <= 256, "tasks must fit one per thread");
    __shared__ __align__(16) float slab[CIN*ROWS_MAX*ROWP];

    int n   = blockIdx.x / VSPLIT;
    int seg = blockIdx.x % VSPLIT;
    int v0 = seg * NVSEG;
    int v1 = (v0 + NVSEG < NV) ? v0 + NVSEG : NV;
    int r0 = (v0 - 2 > 0) ? v0 - 2 : 0;
    int r1m = (v1 - 1 < HIN - 1) ? v1 - 1 : HIN - 1;
    int nrows = r1m - r0 + 1;
    int tid = threadIdx.x;
    const float* inb = in + (size_t)n*CIN*HIN*ISTR;
    const size_t PPSTR = (size_t)CIN*COUT*12;

    for (int e = tid; e < CIN*ROWS_MAX; e += 256) {
        int c = e / ROWS_MAX, ri = e % ROWS_MAX;
        if (ri < nrows) {
            const float* src = inb + ((size_t)c*HIN + r0 + ri)*ISTR;
            float* dst = slab + (c*ROWS_MAX + ri)*ROWP;
            dst[0] = 0.f; dst[1] = 0.f;
            #pragma unroll
            for (int x2 = HIN+2; x2 < ROWP; ++x2) dst[x2] = 0.f;
            for (int x2 = 0; x2 < HIN; ++x2) dst[2+x2] = src[x2];
        }
    }
    __syncthreads();

    int task = tid;
    int vi = task % NVB; int rem = task / NVB;
    int o = rem % COUT;  int tb = rem / COUT;
    int u0 = tb * TWU;
    bool anyv = false;
    int vg[VPER];
    #pragma unroll
    for (int q = 0; q < VPER; ++q) {
        vg[q] = v0 + vi + q*NVB;
        if (vg[q] < v1) anyv = true;
    }
    if (tb >= TB) anyv = false;

    float acc[VPER][2][2][TWU];
    #pragma unroll
    for (int q=0;q<VPER;++q)
        #pragma unroll
        for (int a=0;a<2;++a)
            #pragma unroll
            for (int b=0;b<2;++b)
                #pragma unroll
                for (int t=0;t<TWU;++t) acc[q][a][b][t] = 0.f;

    if (anyv) {
        const float* wb0 = wp + (size_t)o*12;
        for (int c = 0; c < CIN; ++c) {
            const float* wbase = wb0 + (size_t)c*COUT*12;
            const float* sc = slab + c*(ROWS_MAX*ROWP);
            #pragma unroll
            for (int jj = 0; jj < 3; ++jj) {
                float r[VPER][RLEN];
                #pragma unroll
                for (int q = 0; q < VPER; ++q) {
                    int iy = vg[q] - jj;
                    if (iy >= 0 && iy < HIN) {
                        const float* srow = sc + (iy - r0)*ROWP + u0;
                        if constexpr (TWU == 1) {
                            r[q][0] = srow[0]; r[q][1] = srow[1]; r[q][2] = srow[2];
                        } else {
                            #pragma unroll
                            for (int p4 = 0; p4 < NR4; ++p4) {
                                float4 f = *reinterpret_cast<const float4*>(srow + p4*4);
                                r[q][p4*4]=f.x; r[q][p4*4+1]=f.y; r[q][p4*4+2]=f.z; r[q][p4*4+3]=f.w;
                            }
                        }
                    } else {
                        #pragma unroll
                        for (int p4 = 0; p4 < RLEN; ++p4) r[q][p4] = 0.f;
                    }
                }
                #pragma unroll
                for (int pp = 0; pp < 4; ++pp) {
                    float4 w4 = *reinterpret_cast<const float4*>(wbase + pp*PPSTR + jj*4);
                    int py = pp >> 1, px = pp & 1;
                    #pragma unroll
                    for (int q = 0; q < VPER; ++q)
                        #pragma unroll
                        for (int t = 0; t < TWU; ++t)
                            acc[q][py][px][t] =
                                fmaf(w4.x, r[q][t+2],
                                fmaf(w4.y, r[q][t+1],
                                fmaf(w4.z, r[q][t], acc[q][py][px][t])));
                }
            }
        }
        float bv = bias[o];
        #pragma unroll
        for (int q = 0; q < VPER; ++q) {
            if (vg[q] >= v1) continue;
            #pragma unroll
            for (int py = 0; py < 2; ++py) {
                int y = py + 2*vg[q];
                if (y >= HOUT) continue;
                float* ob = out + (((size_t)n*COUT + o)*HOUT + y)*OSTR;
                #pragma unroll
                for (int t = 0; t < TWU; ++t) {
                    int x0 = 2*(u0+t);
                    if (x0 + 1 < HOUT) {
                        float2 qv;
                        qv.x = act_apply<ACT>(acc[q][py][0][t] + bv);
                        qv.y = act_apply<ACT>(acc[q][py][1][t] + bv);
                        *reinterpret_cast<float2*>(ob + x0) = qv;
                    } else if (x0 < HOUT) {
                        ob[x0] = act_apply<ACT>(acc[q][py][0][t] + bv);
                    }
                }
            }
        }
    }
}

// ---------------- launch ----------------
extern "C" void kernel_launch(void* const* d_in, const int* in_sizes, int n_in,
                              void* d_out, int out_size, void* d_ws, size_t ws_size,
                              hipStream_t stream)
{
    const float* x       = (const float*)d_in[0];
    const float* action  = (const float*)d_in[1];
    const float* h0      = (const float*)d_in[2];
    const float* c0      = (const float*)d_in[3];
    const float* conv1_w = (const float*)d_in[4];  const float* conv1_b = (const float*)d_in[5];
    const float* conv2_w = (const float*)d_in[6];  const float* conv2_b = (const float*)d_in[7];
    const float* conv3_w = (const float*)d_in[8];  const float* conv3_b = (const float*)d_in[9];
    const float* conv4_w = (const float*)d_in[10]; const float* conv4_b = (const float*)d_in[11];
    const float* fc1_w   = (const float*)d_in[12]; const float* fc1_b   = (const float*)d_in[13];
    const float* fc2_w   = (const float*)d_in[14]; const float* fc2_b   = (const float*)d_in[15];
    const float* w_ih    = (const float*)d_in[16]; const float* w_hh    = (const float*)d_in[17];
    const float* b_ih    = (const float*)d_in[18]; const float* b_hh    = (const float*)d_in[19];
    const float* fcsd_w  = (const float*)d_in[20]; const float* fcsd_b  = (const float*)d_in[21];
    const float* d1_w    = (const float*)d_in[22]; const float* d1_b    = (const float*)d_in[23];
    const float* d2_w    = (const float*)d_in[24]; const float* d2_b    = (const float*)d_in[25];
    const float* d3_w    = (const float*)d_in[26]; const float* d3_b    = (const float*)d_in[27];
    const float* d4_w    = (const float*)d_in[28]; const float* d4_b    = (const float*)d_in[29];
    const float* fc5_w   = (const float*)d_in[30]; const float* fc5_b   = (const float*)d_in[31];
    float* out = (float*)d_out;
    float* ws  = (float*)d_ws;

    // workspace layout (floats)
    float* a1    = ws;                  // 1,537,600  [50,32,31,31]
    float* a2    = a1 + 1537600;        //   627,200  [50,64,14,14]
    float* a3    = a2 + 627200;         //   230,400  [50,128,6,6]
    float* flat  = a3 + 230400;         //    51,200  [50,1024]
    float* z     = flat + 51200;        //    25,600  [50,512]
    float* fc2o  = z + 25600;           //    51,200  [50,1024]
    float* outs  = fc2o + 51200;        //   870,400  [17,50,1024]
    float* hd    = outs + 870400;       //   870,400  [850,1024]
    float* wp2   = hd + 870400;         //   393,216
    float* wp3   = wp2 + 393216;        //    98,304
    float* wp4   = wp3 + 98304;         //     1,536
    float* y1    = wp4 + 1536;          //  2,720,000  [850,128,5,5]
    float* y2    = y1 + 2720000;        //  9,193,600  [850,64,13,13]
    float* y3    = y2 + 9193600;        // 24,480,000  [850,32,30,30]
    float* xx0T  = y3 + 24480000;       //   131,072  [2048][64]
    float* hTbuf = xx0T + 131072;       //   131,072  ping-pong [2][1024][64]
    // aliased into decoder buffers (dead until after the LSTM):
    float* wsumT = y2;                  //  4,194,304  [1024][4096]
    float* wcatT = y3;                  //  8,388,608  [2048][4096]

    const int B = 50;

    // deconv weight prep
    wprep_kernel<<<(4*128*64*12+255)/256, 256, 0, stream>>>(d2_w, wp2, 128, 64, 5);
    wprep_kernel<<<(4*64*32*12+255)/256, 256, 0, stream>>>(d3_w, wp3, 64, 32, 6);
    wprep_kernel<<<(4*32*1*12+255)/256, 256, 0, stream>>>(d4_w, wp4, 32, 1, 6);

    // LSTM weight transposes: wsumT = (w_ih+w_hh)^T, wcatT = [w_ih^T; w_hh^T]
    {
        dim3 tg(32, 128);
        transpose_w_kernel<<<tg, 256, 0, stream>>>(w_ih, w_hh, wsumT, 0);
        transpose_w_kernel<<<tg, 256, 0, stream>>>(w_ih, nullptr, wcatT, 0);
        transpose_w_kernel<<<tg, 256, 0, stream>>>(w_hh, nullptr, wcatT, 1024);
    }

    // encoder
    conv_enc_kernel<1,32><<<(B*32*31*31+255)/256, 256, 0, stream>>>(x, conv1_w, conv1_b, a1, B, 64, 31);
    conv_enc_kernel<32,64><<<(B*64*14*14+255)/256, 256, 0, stream>>>(a1, conv2_w, conv2_b, a2, B, 31, 14);
    conv_enc_kernel<64,128><<<(B*128*6*6+255)/256, 256, 0, stream>>>(a2, conv3_w, conv3_b, a3, B, 14, 6);
    conv_enc_kernel<128,256><<<(B*256*2*2+255)/256, 256, 0, stream>>>(a3, conv4_w, conv4_b, flat, B, 6, 2);

    // fc1 -> z[:, :482]; action -> z[:, 482:512]; reward head
    {
        dim3 grid((482+63)/64, (B+31)/32, 1);
        gemm_kernel<32,64,32,true,0><<<grid, 128, 0, stream>>>(flat, fc1_w, fc1_b, z, B, 482, 1024, 1024, 512, 1, 0);
    }
    concat_action_kernel<<<(1500+63)/64, 64, 0, stream>>>(action, z);
    reward_kernel<<<1, 64, 0, stream>>>(z, fc5_w, fc5_b, out + (size_t)850*4096);

    // fc2 (leaky relu)
    {
        dim3 grid((1024+63)/64, (B+31)/32, 1);
        gemm_kernel<32,64,32,true,2><<<grid, 128, 0, stream>>>(z, fc2_w, fc2_b, fc2o, B, 1024, 512, 512, 1024, 1, 0);
    }

    // LSTM: stage xx0T = [fc2o^T ; h0^T], then one cooperative kernel
    transpose_bt_kernel<<<(65536+255)/256, 256, 0, stream>>>(fc2o, xx0T);
    transpose_bt_kernel<<<(65536+255)/256, 256, 0, stream>>>(h0, xx0T + 65536);
    {
        void* kargs[] = { (void*)&xx0T, (void*)&wcatT, (void*)&wsumT, (void*)&c0,
                          (void*)&b_ih, (void*)&b_hh, (void*)&hTbuf, (void*)&outs };
        hipLaunchCooperativeKernel((const void*)lstm_coop2_kernel,
                                   dim3(256), dim3(512), kargs, 0, stream);
    }

    // fcsd: hd = leaky(outs @ fcsd_w^T + fcsd_b)   [850,1024]
    {
        dim3 grid((1024+63)/64, (850+63)/64, 1);
        gemm_kernel<64,64,32,true,2><<<grid, 256, 0, stream>>>(outs, fcsd_w, fcsd_b, hd, 850, 1024, 1024, 1024, 1024, 1, 0);
    }
    // d1: 1x1 spatial input -> pure GEMM [850,1024]x[1024,3200], tanh
    // (overwrites y1; y2/y3 aliases of wsumT/wcatT are dead after the LSTM)
    {
        dim3 grid((3200+63)/64, (850+63)/64, 1);
        gemm_kernel<64,64,32,false,1><<<grid, 256, 0, stream>>>(hd, d1_w, d1_b, y1, 850, 3200, 1024, 1024, 3200, 25, 0);
    }

    // d2/d3/d4: round-4 best configs (unpadded strides)
    deconv4_kernel<128,64,5,13,1, 1,12,7,2,1,3, 5,13><<<850, 256, 0, stream>>>(y1, wp2, d2_b, y2);
    deconv4_kernel<64,32,13,30,1, 2,20,15,1,1,3, 13,30><<<1700, 256, 0, stream>>>(y2, wp3, d3_b, y3);
    deconv4_kernel<32,1,30,64,0, 4,36,1,1,32,3, 30,64><<<3400, 256, 0, stream>>>(y3, wp4, d4_b, out);

    (void)in_sizes; (void)n_in; (void)out_size; (void)ws_size;
}

// Round 8
// 4463.501 us; speedup vs baseline: 1.0418x; 1.0146x over previous
//
#include <hip/hip_runtime.h>
#include <hip/hip_cooperative_groups.h>
#include <math.h>

namespace cg = cooperative_groups;

#define DI __device__ __forceinline__

DI float sigm(float x){ return 1.0f/(1.0f+expf(-x)); }
DI float lrelu(float x){ return x > 0.f ? x : 0.01f*x; }

template<int ACT>
DI float act_apply(float v){
    if (ACT == 1) return tanhf(v);
    if (ACT == 2) return lrelu(v);
    return v;
}

// ---------------- encoder conv: stride 2, 4x4, tanh ----------------
template<int CIN, int COUT>
__global__ __launch_bounds__(256)
void conv_enc_kernel(const float* __restrict__ in, const float* __restrict__ w,
                     const float* __restrict__ bias, float* __restrict__ out,
                     int N, int H, int OH)
{
    int idx = blockIdx.x*256 + threadIdx.x;
    int total = N*COUT*OH*OH;
    if (idx >= total) return;
    int ox = idx % OH; int t = idx / OH;
    int oy = t % OH;   t /= OH;
    int o  = t % COUT; int n = t / COUT;
    float acc = bias[o];
    const float* wp = w + o*CIN*16;
    const float* ip = in + ((size_t)n*CIN)*H*H + (oy*2)*H + ox*2;
    for (int c = 0; c < CIN; ++c) {
        const float* ipc = ip + c*H*H;
        const float* wpc = wp + c*16;
        #pragma unroll
        for (int ky = 0; ky < 4; ++ky)
            #pragma unroll
            for (int kx = 0; kx < 4; ++kx)
                acc = fmaf(ipc[ky*H + kx], wpc[ky*4 + kx], acc);
    }
    out[idx] = tanhf(acc);
}

// ---------------- tiled GEMM: C = act(A @ op(B) + bias) ----------------
template<int BM,int BN,int BK,bool BT,int ACT>
__global__ __launch_bounds__((BM/4)*(BN/4))
void gemm_kernel(const float* __restrict__ A, const float* __restrict__ Bm,
                 const float* __restrict__ bias, float* __restrict__ C,
                 int M, int N, int Kfull, int klen, int ldc, int bias_div,
                 long partStride)
{
    constexpr int TM = 4, TN = 4;
    constexpr int THREADS = (BM/TM)*(BN/TN);
    constexpr int LDA = BM + 4, LDB = BN + 4;
    __shared__ __align__(16) float As[BK][LDA];
    __shared__ __align__(16) float Bs[BK][LDB];
    int tid = threadIdx.x;
    int m0 = blockIdx.y * BM, n0 = blockIdx.x * BN;
    int koff = blockIdx.z * klen;
    C += (long)blockIdx.z * partStride;
    constexpr int NTX = BN/TN;
    int tx = tid % NTX, ty = tid / NTX;
    float acc[4][4];
    #pragma unroll
    for (int i=0;i<4;++i)
        #pragma unroll
        for (int j=0;j<4;++j) acc[i][j] = 0.f;

    for (int k0 = 0; k0 < klen; k0 += BK) {
        for (int e = tid; e < BM*BK; e += THREADS) {
            int k = e % BK, m = e / BK;
            As[k][m] = (m0+m < M) ? A[(size_t)(m0+m)*Kfull + koff + k0 + k] : 0.f;
        }
        if (BT) {
            for (int e = tid; e < BN*BK; e += THREADS) {
                int k = e % BK, n = e / BK;
                Bs[k][n] = (n0+n < N) ? Bm[(size_t)(n0+n)*Kfull + koff + k0 + k] : 0.f;
            }
        } else {
            for (int e = tid; e < BN*BK; e += THREADS) {
                int n = e % BN, k = e / BN;
                Bs[k][n] = (n0+n < N) ? Bm[(size_t)(koff + k0 + k)*N + n0+n] : 0.f;
            }
        }
        __syncthreads();
        #pragma unroll 8
        for (int k = 0; k < BK; ++k) {
            float4 a4 = *reinterpret_cast<const float4*>(&As[k][ty*4]);
            float4 b4 = *reinterpret_cast<const float4*>(&Bs[k][tx*4]);
            float av[4] = {a4.x, a4.y, a4.z, a4.w};
            float bv[4] = {b4.x, b4.y, b4.z, b4.w};
            #pragma unroll
            for (int i=0;i<4;++i)
                #pragma unroll
                for (int j=0;j<4;++j)
                    acc[i][j] = fmaf(av[i], bv[j], acc[i][j]);
        }
        __syncthreads();
    }
    #pragma unroll
    for (int i=0;i<4;++i) {
        int m = m0 + ty*4 + i;
        if (m >= M) continue;
        #pragma unroll
        for (int j=0;j<4;++j) {
            int n = n0 + tx*4 + j;
            if (n >= N) continue;
            float v = acc[i][j] + (bias ? bias[n / bias_div] : 0.f);
            C[(size_t)m*ldc + n] = act_apply<ACT>(v);
        }
    }
}

// ---------------- small helpers ----------------
__global__ __launch_bounds__(64)
void concat_action_kernel(const float* __restrict__ action, float* __restrict__ z)
{
    int i = blockIdx.x*64 + threadIdx.x;
    if (i < 50*30) { int b = i/30, k = i%30; z[b*512 + 482 + k] = action[i]; }
}

__global__ __launch_bounds__(64)
void reward_kernel(const float* __restrict__ z, const float* __restrict__ w,
                   const float* __restrict__ b, float* __restrict__ out)
{
    int bi = threadIdx.x;
    if (bi < 50) {
        float acc = b[0];
        for (int k = 0; k < 512; ++k) acc = fmaf(z[bi*512 + k], w[k], acc);
        out[bi] = acc;
    }
}

// transpose [50][1024] -> [1024][64] (zero-padded cols 50..63)
__global__ __launch_bounds__(256)
void transpose_bt_kernel(const float* __restrict__ in, float* __restrict__ out)
{
    int idx = blockIdx.x*256 + threadIdx.x;
    if (idx >= 1024*64) return;
    int j = idx >> 6, b = idx & 63;
    out[idx] = (b < 50) ? in[(size_t)b*1024 + j] : 0.f;
}

// ---------------- LSTM weight pack ----------------
// outp[((blk*KLEN) + k)*16 + j] = src(row(j,blk), k) where
// row = 4*blk + (j&3) + 1024*(j>>2).
// mode 0 (KLEN=1024): src = w_ih[row][k] + w_hh[row][k]
// mode 1 (KLEN=2048): src = k<1024 ? w_ih[row][k] : w_hh[row][k-1024]
__global__ __launch_bounds__(256)
void wpack_kernel(const float* __restrict__ wih, const float* __restrict__ whh,
                  float* __restrict__ outp, int mode)
{
    __shared__ float tile[16][66];
    int blk = blockIdx.x;
    int k0  = blockIdx.y * 64;
    int tid = threadIdx.x;
    const int KLEN = mode ? 2048 : 1024;
    {
        int r = tid >> 6, kk = tid & 63;      // 4 rows per pass
        #pragma unroll
        for (int rr = 0; rr < 4; ++rr) {
            int r2 = r + rr*4;
            int row = 4*blk + (r2 & 3) + 1024*(r2 >> 2);
            int kg = k0 + kk;
            float v;
            if (mode == 0)
                v = wih[(size_t)row*1024 + kg] + whh[(size_t)row*1024 + kg];
            else
                v = (kg < 1024) ? wih[(size_t)row*1024 + kg]
                                : whh[(size_t)row*1024 + kg - 1024];
            tile[r2][kk] = v;
        }
    }
    __syncthreads();
    {
        int j = tid & 15, kk = tid >> 4;      // 16 k per pass
        #pragma unroll
        for (int kq = 0; kq < 4; ++kq) {
            int k = kk + kq*16;
            outp[((size_t)blk*KLEN + k0 + k)*16 + j] = tile[j][k];
        }
    }
}

// ---------------- cooperative fused LSTM v3: packed weights -----------------
// 256 blocks x 512 threads. Block owns 16 gate-rows {g*1024 + 4blk + i}, all
// 64 batch cols. Wave ks = k-slice. Lane (rg,cg): 4x4 register tile; per k:
// 1 float4 w-load from wpack (contiguous 64B/line per wave, L3/L2-hot) +
// 1 float4 x-load (contiguous 256B/row) + 16 FMAs. LDS reduce of 8 partials.
__global__ __launch_bounds__(512)
void lstm_coop3_kernel(const float* __restrict__ xx0T, const float* __restrict__ wpack0,
                       const float* __restrict__ wpack, const float* __restrict__ c0,
                       const float* __restrict__ b_ih, const float* __restrict__ b_hh,
                       float* __restrict__ hTbuf, float* __restrict__ outs)
{
    __shared__ float gpart[8][16][68];
    __shared__ float cst[4][50];
    __shared__ float ldsb[16];
    const int blk = blockIdx.x;
    const int tid = threadIdx.x;
    const int ks  = tid >> 6;        // 0..7 (wave)
    const int lane = tid & 63;
    const int rg  = lane >> 4;       // gate group 0..3
    const int cg  = lane & 15;       // col group 0..15

    if (tid < 16) {
        int row = 4*blk + (tid & 3) + 1024*(tid >> 2);
        ldsb[tid] = b_ih[row] + b_hh[row];
    }
    if (tid < 200) {
        int ci = tid & 3, b = tid >> 2;
        cst[ci][b] = c0[(size_t)b*1024 + 4*blk + ci];
    }
    cg::grid_group grid = cg::this_grid();

    for (int t = 0; t < 17; ++t) {
        const float* xptr; const float* wptr; int klen;
        if (t == 0) {
            klen = 256;
            xptr = xx0T + (size_t)(ks*klen)*64 + cg*4;
            wptr = wpack0 + ((size_t)blk*2048 + ks*klen)*16 + rg*4;
        } else {
            klen = 128;
            xptr = hTbuf + (size_t)(t & 1)*65536 + (size_t)(ks*klen)*64 + cg*4;
            wptr = wpack + ((size_t)blk*1024 + ks*klen)*16 + rg*4;
        }
        float acc[4][4];
        #pragma unroll
        for (int i=0;i<4;++i)
            #pragma unroll
            for (int j=0;j<4;++j) acc[i][j] = 0.f;
        #pragma unroll 8
        for (int kk = 0; kk < klen; ++kk) {
            float4 w4 = *reinterpret_cast<const float4*>(wptr);
            float4 x4 = *reinterpret_cast<const float4*>(xptr);
            wptr += 16; xptr += 64;
            float wv[4] = {w4.x, w4.y, w4.z, w4.w};
            float xv[4] = {x4.x, x4.y, x4.z, x4.w};
            #pragma unroll
            for (int i=0;i<4;++i)
                #pragma unroll
                for (int j=0;j<4;++j)
                    acc[i][j] = fmaf(wv[i], xv[j], acc[i][j]);
        }
        __syncthreads();   // prev-step reduce finished before gpart overwrite
        #pragma unroll
        for (int i = 0; i < 4; ++i) {
            float4 v = make_float4(acc[i][0], acc[i][1], acc[i][2], acc[i][3]);
            *reinterpret_cast<float4*>(&gpart[ks][rg*4 + i][cg*4]) = v;
        }
        __syncthreads();
        if (tid < 200) {
            int ci = tid & 3, b = tid >> 2;
            float s0 = ldsb[ci], s1 = ldsb[4+ci], s2 = ldsb[8+ci], s3 = ldsb[12+ci];
            #pragma unroll
            for (int p = 0; p < 8; ++p) {
                s0 += gpart[p][ci][b];    s1 += gpart[p][4+ci][b];
                s2 += gpart[p][8+ci][b];  s3 += gpart[p][12+ci][b];
            }
            float c = sigm(s1)*cst[ci][b] + sigm(s0)*tanhf(s2);
            float h = sigm(s3)*tanhf(c);
            cst[ci][b] = c;
            int col = 4*blk + ci;
            hTbuf[(size_t)((t + 1) & 1)*65536 + (size_t)col*64 + b] = h;
            outs[(size_t)t*51200 + (size_t)b*1024 + col] = h;
        }
        if (t < 16) { __threadfence(); grid.sync(); }
    }
}

// ---------------- weight prep for parity-decomposed deconv ----------------
__global__ __launch_bounds__(256)
void wprep_kernel(const float* __restrict__ w, float* __restrict__ wp,
                  int CIN, int COUT, int KS)
{
    int idx = blockIdx.x*256 + threadIdx.x;
    int total = 4*CIN*COUT*12;
    if (idx >= total) return;
    int slot = idx % 12; int rem = idx / 12;
    int o = rem % COUT; rem /= COUT;
    int c = rem % CIN;  int pp = rem / CIN;
    int py = pp >> 1, px = pp & 1;
    int j = slot >> 2, i = slot & 3;
    int ky = py + 2*j, kx = px + 2*i;
    float v = 0.f;
    if (i < 3 && ky < KS && kx < KS)
        v = w[(((size_t)c*COUT + o)*KS + ky)*KS + kx];
    wp[idx] = v;
}

// ---------------- parity-merged transposed conv, v-split blocks -------------
template<int CIN,int COUT,int HIN,int HOUT,int ACT,int VSPLIT,int ROWP,int TWU,
         int VPER,int TB,int MWAVES,int ISTR,int OSTR>
__global__ __launch_bounds__(256, MWAVES)
void deconv4_kernel(const float* __restrict__ in, const float* __restrict__ wp,
                    const float* __restrict__ bias, float* __restrict__ out)
{
    constexpr int NV = (HOUT + 1) / 2;
    constexpr int NVSEG = (NV + VSPLIT - 1) / VSPLIT;
    constexpr int NVB = (NVSEG + VPER - 1) / VPER;
    constexpr int ROWS_MAX = (NVSEG + 2 < HIN) ? (NVSEG + 2) : HIN;
    constexpr int NR4 = (TWU + 2 + 3) / 4;
    constexpr int RLEN = (TWU == 1) ? 4 : NR4*4;
    static_assert(NVB * COUT * TB <= 256, "tasks must fit one per thread");
    __shared__ __align__(16) float slab[CIN*ROWS_MAX*ROWP];

    int n   = blockIdx.x / VSPLIT;
    int seg = blockIdx.x % VSPLIT;
    int v0 = seg * NVSEG;
    int v1 = (v0 + NVSEG < NV) ? v0 + NVSEG : NV;
    int r0 = (v0 - 2 > 0) ? v0 - 2 : 0;
    int r1m = (v1 - 1 < HIN - 1) ? v1 - 1 : HIN - 1;
    int nrows = r1m - r0 + 1;
    int tid = threadIdx.x;
    const float* inb = in + (size_t)n*CIN*HIN*ISTR;
    const size_t PPSTR = (size_t)CIN*COUT*12;

    for (int e = tid; e < CIN*ROWS_MAX; e += 256) {
        int c = e / ROWS_MAX, ri = e % ROWS_MAX;
        if (ri < nrows) {
            const float* src = inb + ((size_t)c*HIN + r0 + ri)*ISTR;
            float* dst = slab + (c*ROWS_MAX + ri)*ROWP;
            dst[0] = 0.f; dst[1] = 0.f;
            #pragma unroll
            for (int x2 = HIN+2; x2 < ROWP; ++x2) dst[x2] = 0.f;
            for (int x2 = 0; x2 < HIN; ++x2) dst[2+x2] = src[x2];
        }
    }
    __syncthreads();

    int task = tid;
    int vi = task % NVB; int rem = task / NVB;
    int o = rem % COUT;  int tb = rem / COUT;
    int u0 = tb * TWU;
    bool anyv = false;
    int vg[VPER];
    #pragma unroll
    for (int q = 0; q < VPER; ++q) {
        vg[q] = v0 + vi + q*NVB;
        if (vg[q] < v1) anyv = true;
    }
    if (tb >= TB) anyv = false;

    float acc[VPER][2][2][TWU];
    #pragma unroll
    for (int q=0;q<VPER;++q)
        #pragma unroll
        for (int a=0;a<2;++a)
            #pragma unroll
            for (int b=0;b<2;++b)
                #pragma unroll
                for (int t=0;t<TWU;++t) acc[q][a][b][t] = 0.f;

    if (anyv) {
        const float* wb0 = wp + (size_t)o*12;
        for (int c = 0; c < CIN; ++c) {
            const float* wbase = wb0 + (size_t)c*COUT*12;
            const float* sc = slab + c*(ROWS_MAX*ROWP);
            #pragma unroll
            for (int jj = 0; jj < 3; ++jj) {
                float r[VPER][RLEN];
                #pragma unroll
                for (int q = 0; q < VPER; ++q) {
                    int iy = vg[q] - jj;
                    if (iy >= 0 && iy < HIN) {
                        const float* srow = sc + (iy - r0)*ROWP + u0;
                        if constexpr (TWU == 1) {
                            r[q][0] = srow[0]; r[q][1] = srow[1]; r[q][2] = srow[2];
                        } else {
                            #pragma unroll
                            for (int p4 = 0; p4 < NR4; ++p4) {
                                float4 f = *reinterpret_cast<const float4*>(srow + p4*4);
                                r[q][p4*4]=f.x; r[q][p4*4+1]=f.y; r[q][p4*4+2]=f.z; r[q][p4*4+3]=f.w;
                            }
                        }
                    } else {
                        #pragma unroll
                        for (int p4 = 0; p4 < RLEN; ++p4) r[q][p4] = 0.f;
                    }
                }
                #pragma unroll
                for (int pp = 0; pp < 4; ++pp) {
                    float4 w4 = *reinterpret_cast<const float4*>(wbase + pp*PPSTR + jj*4);
                    int py = pp >> 1, px = pp & 1;
                    #pragma unroll
                    for (int q = 0; q < VPER; ++q)
                        #pragma unroll
                        for (int t = 0; t < TWU; ++t)
                            acc[q][py][px][t] =
                                fmaf(w4.x, r[q][t+2],
                                fmaf(w4.y, r[q][t+1],
                                fmaf(w4.z, r[q][t], acc[q][py][px][t])));
                }
            }
        }
        float bv = bias[o];
        #pragma unroll
        for (int q = 0; q < VPER; ++q) {
            if (vg[q] >= v1) continue;
            #pragma unroll
            for (int py = 0; py < 2; ++py) {
                int y = py + 2*vg[q];
                if (y >= HOUT) continue;
                float* ob = out + (((size_t)n*COUT + o)*HOUT + y)*OSTR;
                #pragma unroll
                for (int t = 0; t < TWU; ++t) {
                    int x0 = 2*(u0+t);
                    if (x0 + 1 < HOUT) {
                        float2 qv;
                        qv.x = act_apply<ACT>(acc[q][py][0][t] + bv);
                        qv.y = act_apply<ACT>(acc[q][py][1][t] + bv);
                        *reinterpret_cast<float2*>(ob + x0) = qv;
                    } else if (x0 < HOUT) {
                        ob[x0] = act_apply<ACT>(acc[q][py][0][t] + bv);
                    }
                }
            }
        }
    }
}

// ---------------- launch ----------------
extern "C" void kernel_launch(void* const* d_in, const int* in_sizes, int n_in,
                              void* d_out, int out_size, void* d_ws, size_t ws_size,
                              hipStream_t stream)
{
    const float* x       = (const float*)d_in[0];
    const float* action  = (const float*)d_in[1];
    const float* h0      = (const float*)d_in[2];
    const float* c0      = (const float*)d_in[3];
    const float* conv1_w = (const float*)d_in[4];  const float* conv1_b = (const float*)d_in[5];
    const float* conv2_w = (const float*)d_in[6];  const float* conv2_b = (const float*)d_in[7];
    const float* conv3_w = (const float*)d_in[8];  const float* conv3_b = (const float*)d_in[9];
    const float* conv4_w = (const float*)d_in[10]; const float* conv4_b = (const float*)d_in[11];
    const float* fc1_w   = (const float*)d_in[12]; const float* fc1_b   = (const float*)d_in[13];
    const float* fc2_w   = (const float*)d_in[14]; const float* fc2_b   = (const float*)d_in[15];
    const float* w_ih    = (const float*)d_in[16]; const float* w_hh    = (const float*)d_in[17];
    const float* b_ih    = (const float*)d_in[18]; const float* b_hh    = (const float*)d_in[19];
    const float* fcsd_w  = (const float*)d_in[20]; const float* fcsd_b  = (const float*)d_in[21];
    const float* d1_w    = (const float*)d_in[22]; const float* d1_b    = (const float*)d_in[23];
    const float* d2_w    = (const float*)d_in[24]; const float* d2_b    = (const float*)d_in[25];
    const float* d3_w    = (const float*)d_in[26]; const float* d3_b    = (const float*)d_in[27];
    const float* d4_w    = (const float*)d_in[28]; const float* d4_b    = (const float*)d_in[29];
    const float* fc5_w   = (const float*)d_in[30]; const float* fc5_b   = (const float*)d_in[31];
    float* out = (float*)d_out;
    float* ws  = (float*)d_ws;

    // workspace layout (floats)
    float* a1    = ws;                  // 1,537,600  [50,32,31,31]
    float* a2    = a1 + 1537600;        //   627,200  [50,64,14,14]
    float* a3    = a2 + 627200;         //   230,400  [50,128,6,6]
    float* flat  = a3 + 230400;         //    51,200  [50,1024]
    float* z     = flat + 51200;        //    25,600  [50,512]
    float* fc2o  = z + 25600;           //    51,200  [50,1024]
    float* outs  = fc2o + 51200;        //   870,400  [17,50,1024]
    float* hd    = outs + 870400;       //   870,400  [850,1024]
    float* wp2   = hd + 870400;         //   393,216
    float* wp3   = wp2 + 393216;        //    98,304
    float* wp4   = wp3 + 98304;         //     1,536
    float* y1    = wp4 + 1536;          //  2,720,000  [850,128,5,5]
    float* y2    = y1 + 2720000;        //  9,193,600  [850,64,13,13]
    float* y3    = y2 + 9193600;        // 24,480,000  [850,32,30,30]
    float* xx0T  = y3 + 24480000;       //   131,072  [2048][64]
    float* hTbuf = xx0T + 131072;       //   131,072  ping-pong [2][1024][64]
    // aliased into decoder buffers (dead until after the LSTM):
    float* wpack  = y2;                 //  4,194,304  [256][1024][16]
    float* wpack0 = y3;                 //  8,388,608  [256][2048][16]

    const int B = 50;

    // deconv weight prep
    wprep_kernel<<<(4*128*64*12+255)/256, 256, 0, stream>>>(d2_w, wp2, 128, 64, 5);
    wprep_kernel<<<(4*64*32*12+255)/256, 256, 0, stream>>>(d3_w, wp3, 64, 32, 6);
    wprep_kernel<<<(4*32*1*12+255)/256, 256, 0, stream>>>(d4_w, wp4, 32, 1, 6);

    // LSTM weight packs (per-block contiguous)
    wpack_kernel<<<dim3(256, 16), 256, 0, stream>>>(w_ih, w_hh, wpack, 0);
    wpack_kernel<<<dim3(256, 32), 256, 0, stream>>>(w_ih, w_hh, wpack0, 1);

    // encoder
    conv_enc_kernel<1,32><<<(B*32*31*31+255)/256, 256, 0, stream>>>(x, conv1_w, conv1_b, a1, B, 64, 31);
    conv_enc_kernel<32,64><<<(B*64*14*14+255)/256, 256, 0, stream>>>(a1, conv2_w, conv2_b, a2, B, 31, 14);
    conv_enc_kernel<64,128><<<(B*128*6*6+255)/256, 256, 0, stream>>>(a2, conv3_w, conv3_b, a3, B, 14, 6);
    conv_enc_kernel<128,256><<<(B*256*2*2+255)/256, 256, 0, stream>>>(a3, conv4_w, conv4_b, flat, B, 6, 2);

    // fc1 -> z[:, :482]; action -> z[:, 482:512]; reward head
    {
        dim3 grid((482+63)/64, (B+31)/32, 1);
        gemm_kernel<32,64,32,true,0><<<grid, 128, 0, stream>>>(flat, fc1_w, fc1_b, z, B, 482, 1024, 1024, 512, 1, 0);
    }
    concat_action_kernel<<<(1500+63)/64, 64, 0, stream>>>(action, z);
    reward_kernel<<<1, 64, 0, stream>>>(z, fc5_w, fc5_b, out + (size_t)850*4096);

    // fc2 (leaky relu)
    {
        dim3 grid((1024+63)/64, (B+31)/32, 1);
        gemm_kernel<32,64,32,true,2><<<grid, 128, 0, stream>>>(z, fc2_w, fc2_b, fc2o, B, 1024, 512, 512, 1024, 1, 0);
    }

    // LSTM: stage xx0T = [fc2o^T ; h0^T], then one cooperative kernel
    transpose_bt_kernel<<<(65536+255)/256, 256, 0, stream>>>(fc2o, xx0T);
    transpose_bt_kernel<<<(65536+255)/256, 256, 0, stream>>>(h0, xx0T + 65536);
    {
        void* kargs[] = { (void*)&xx0T, (void*)&wpack0, (void*)&wpack, (void*)&c0,
                          (void*)&b_ih, (void*)&b_hh, (void*)&hTbuf, (void*)&outs };
        hipLaunchCooperativeKernel((const void*)lstm_coop3_kernel,
                                   dim3(256), dim3(512), kargs, 0, stream);
    }

    // fcsd: hd = leaky(outs @ fcsd_w^T + fcsd_b)   [850,1024]
    {
        dim3 grid((1024+63)/64, (850+63)/64, 1);
        gemm_kernel<64,64,32,true,2><<<grid, 256, 0, stream>>>(outs, fcsd_w, fcsd_b, hd, 850, 1024, 1024, 1024, 1024, 1, 0);
    }
    // d1: 1x1 spatial input -> pure GEMM [850,1024]x[1024,3200], tanh
    // (overwrites y1; y2/y3 aliases of wpack/wpack0 are dead after the LSTM)
    {
        dim3 grid((3200+63)/64, (850+63)/64, 1);
        gemm_kernel<64,64,32,false,1><<<grid, 256, 0, stream>>>(hd, d1_w, d1_b, y1, 850, 3200, 1024, 1024, 3200, 25, 0);
    }

    // d2/d3/d4: round-4 best configs (unpadded strides)
    deconv4_kernel<128,64,5,13,1, 1,12,7,2,1,3, 5,13><<<850, 256, 0, stream>>>(y1, wp2, d2_b, y2);
    deconv4_kernel<64,32,13,30,1, 2,20,15,1,1,3, 13,30><<<1700, 256, 0, stream>>>(y2, wp3, d3_b, y3);
    deconv4_kernel<32,1,30,64,0, 4,36,1,1,32,3, 30,64><<<3400, 256, 0, stream>>>(y3, wp4, d4_b, out);

    (void)in_sizes; (void)n_in; (void)out_size; (void)ws_size;
}

// Round 11
// 2826.780 us; speedup vs baseline: 1.6450x; 1.5790x over previous
//
#include <hip/hip_runtime.h>
#include <math.h>

#define DI __device__ __forceinline__

DI float sigm(float x){ return 1.0f/(1.0f+expf(-x)); }
DI float lrelu(float x){ return x > 0.f ? x : 0.01f*x; }

template<int ACT>
DI float act_apply(float v){
    if (ACT == 1) return tanhf(v);
    if (ACT == 2) return lrelu(v);
    return v;
}

// ---------------- encoder conv: stride 2, 4x4, tanh ----------------
template<int CIN, int COUT>
__global__ __launch_bounds__(256)
void conv_enc_kernel(const float* __restrict__ in, const float* __restrict__ w,
                     const float* __restrict__ bias, float* __restrict__ out,
                     int N, int H, int OH)
{
    int idx = blockIdx.x*256 + threadIdx.x;
    int total = N*COUT*OH*OH;
    if (idx >= total) return;
    int ox = idx % OH; int t = idx / OH;
    int oy = t % OH;   t /= OH;
    int o  = t % COUT; int n = t / COUT;
    float acc = bias[o];
    const float* wp = w + o*CIN*16;
    const float* ip = in + ((size_t)n*CIN)*H*H + (oy*2)*H + ox*2;
    for (int c = 0; c < CIN; ++c) {
        const float* ipc = ip + c*H*H;
        const float* wpc = wp + c*16;
        #pragma unroll
        for (int ky = 0; ky < 4; ++ky)
            #pragma unroll
            for (int kx = 0; kx < 4; ++kx)
                acc = fmaf(ipc[ky*H + kx], wpc[ky*4 + kx], acc);
    }
    out[idx] = tanhf(acc);
}

// ---------------- tiled GEMM: C = act(A @ op(B) + bias) ----------------
template<int BM,int BN,int BK,bool BT,int ACT>
__global__ __launch_bounds__((BM/4)*(BN/4))
void gemm_kernel(const float* __restrict__ A, const float* __restrict__ Bm,
                 const float* __restrict__ bias, float* __restrict__ C,
                 int M, int N, int Kfull, int klen, int ldc, int bias_div,
                 long partStride)
{
    constexpr int TM = 4, TN = 4;
    constexpr int THREADS = (BM/TM)*(BN/TN);
    constexpr int LDA = BM + 4, LDB = BN + 4;
    __shared__ __align__(16) float As[BK][LDA];
    __shared__ __align__(16) float Bs[BK][LDB];
    int tid = threadIdx.x;
    int m0 = blockIdx.y * BM, n0 = blockIdx.x * BN;
    int koff = blockIdx.z * klen;
    C += (long)blockIdx.z * partStride;
    constexpr int NTX = BN/TN;
    int tx = tid % NTX, ty = tid / NTX;
    float acc[4][4];
    #pragma unroll
    for (int i=0;i<4;++i)
        #pragma unroll
        for (int j=0;j<4;++j) acc[i][j] = 0.f;

    for (int k0 = 0; k0 < klen; k0 += BK) {
        for (int e = tid; e < BM*BK; e += THREADS) {
            int k = e % BK, m = e / BK;
            As[k][m] = (m0+m < M) ? A[(size_t)(m0+m)*Kfull + koff + k0 + k] : 0.f;
        }
        if (BT) {
            for (int e = tid; e < BN*BK; e += THREADS) {
                int k = e % BK, n = e / BK;
                Bs[k][n] = (n0+n < N) ? Bm[(size_t)(n0+n)*Kfull + koff + k0 + k] : 0.f;
            }
        } else {
            for (int e = tid; e < BN*BK; e += THREADS) {
                int n = e % BN, k = e / BN;
                Bs[k][n] = (n0+n < N) ? Bm[(size_t)(koff + k0 + k)*N + n0+n] : 0.f;
            }
        }
        __syncthreads();
        #pragma unroll 8
        for (int k = 0; k < BK; ++k) {
            float4 a4 = *reinterpret_cast<const float4*>(&As[k][ty*4]);
            float4 b4 = *reinterpret_cast<const float4*>(&Bs[k][tx*4]);
            float av[4] = {a4.x, a4.y, a4.z, a4.w};
            float bv[4] = {b4.x, b4.y, b4.z, b4.w};
            #pragma unroll
            for (int i=0;i<4;++i)
                #pragma unroll
                for (int j=0;j<4;++j)
                    acc[i][j] = fmaf(av[i], bv[j], acc[i][j]);
        }
        __syncthreads();
    }
    #pragma unroll
    for (int i=0;i<4;++i) {
        int m = m0 + ty*4 + i;
        if (m >= M) continue;
        #pragma unroll
        for (int j=0;j<4;++j) {
            int n = n0 + tx*4 + j;
            if (n >= N) continue;
            float v = acc[i][j] + (bias ? bias[n / bias_div] : 0.f);
            C[(size_t)m*ldc + n] = act_apply<ACT>(v);
        }
    }
}

// ---------------- small helpers ----------------
__global__ __launch_bounds__(64)
void concat_action_kernel(const float* __restrict__ action, float* __restrict__ z)
{
    int i = blockIdx.x*64 + threadIdx.x;
    if (i < 50*30) { int b = i/30, k = i%30; z[b*512 + 482 + k] = action[i]; }
}

__global__ __launch_bounds__(64)
void reward_kernel(const float* __restrict__ z, const float* __restrict__ w,
                   const float* __restrict__ b, float* __restrict__ out)
{
    int bi = threadIdx.x;
    if (bi < 50) {
        float acc = b[0];
        for (int k = 0; k < 512; ++k) acc = fmaf(z[bi*512 + k], w[k], acc);
        out[bi] = acc;
    }
}

// transpose [50][1024] -> [1024][64] (zero-padded cols 50..63)
__global__ __launch_bounds__(256)
void transpose_bt_kernel(const float* __restrict__ in, float* __restrict__ out)
{
    int idx = blockIdx.x*256 + threadIdx.x;
    if (idx >= 1024*64) return;
    int j = idx >> 6, b = idx & 63;
    out[idx] = (b < 50) ? in[(size_t)b*1024 + j] : 0.f;
}

// ---------------- LSTM weight pack ----------------
// outp[((blk*KLEN) + k)*16 + j] = src(row(j,blk), k),
// row = 4*blk + (j&3) + 1024*(j>>2).
// mode 0 (KLEN=1024): src = w_ih[row][k] + w_hh[row][k]
// mode 1 (KLEN=2048): src = k<1024 ? w_ih[row][k] : w_hh[row][k-1024]
__global__ __launch_bounds__(256)
void wpack_kernel(const float* __restrict__ wih, const float* __restrict__ whh,
                  float* __restrict__ outp, int mode)
{
    __shared__ float tile[16][66];
    int blk = blockIdx.x;
    int k0  = blockIdx.y * 64;
    int tid = threadIdx.x;
    const int KLEN = mode ? 2048 : 1024;
    {
        int r = tid >> 6, kk = tid & 63;
        #pragma unroll
        for (int rr = 0; rr < 4; ++rr) {
            int r2 = r + rr*4;
            int row = 4*blk + (r2 & 3) + 1024*(r2 >> 2);
            int kg = k0 + kk;
            float v;
            if (mode == 0)
                v = wih[(size_t)row*1024 + kg] + whh[(size_t)row*1024 + kg];
            else
                v = (kg < 1024) ? wih[(size_t)row*1024 + kg]
                                : whh[(size_t)row*1024 + kg - 1024];
            tile[r2][kk] = v;
        }
    }
    __syncthreads();
    {
        int j = tid & 15, kk = tid >> 4;
        #pragma unroll
        for (int kq = 0; kq < 4; ++kq) {
            int k = kk + kq*16;
            outp[((size_t)blk*KLEN + k0 + k)*16 + j] = tile[j][k];
        }
    }
}

// bsumP[blk*16 + j] = b_ih[row] + b_hh[row], row = 4blk + (j&3) + 1024*(j>>2)
__global__ __launch_bounds__(256)
void bsum_pack_kernel(const float* __restrict__ b_ih, const float* __restrict__ b_hh,
                      float* __restrict__ bsumP)
{
    int idx = blockIdx.x*256 + threadIdx.x;
    if (idx >= 4096) return;
    int blk = idx >> 4, j = idx & 15;
    int row = 4*blk + (j & 3) + 1024*(j >> 2);
    bsumP[idx] = b_ih[row] + b_hh[row];
}

// ---------------- LSTM single step (non-cooperative) ------------------------
// 256 blocks x 512 threads. Block owns 16 gate-rows {g*1024+4blk+i}, 64 batch
// cols. Wave ks = k-slice; lane (rg,cg) = 4x4 register tile. 4-deep register
// prefetch keeps 8 loads in flight. Gates fused; h/c round-trip via global
// (kernel boundary provides the cross-step barrier + coherence).
template<int STEP0>
__global__ __launch_bounds__(512)
void lstm_step_kernel(const float* __restrict__ xT, const float* __restrict__ wpk,
                      const float* __restrict__ bsumP, float* __restrict__ cT,
                      float* __restrict__ hTnext, float* __restrict__ outs_t)
{
    constexpr int KTOT = STEP0 ? 2048 : 1024;
    constexpr int KLEN = KTOT / 8;
    __shared__ float gpart[8][16][68];
    const int blk = blockIdx.x;
    const int tid = threadIdx.x;
    const int ks  = tid >> 6;
    const int lane = tid & 63;
    const int rg  = lane >> 4;
    const int cg  = lane & 15;

    const float* xptr = xT + (size_t)(ks*KLEN)*64 + cg*4;
    const float* wptr = wpk + ((size_t)blk*KTOT + ks*KLEN)*16 + rg*4;

    float acc[4][4];
    #pragma unroll
    for (int i=0;i<4;++i)
        #pragma unroll
        for (int j=0;j<4;++j) acc[i][j] = 0.f;

    float4 wb[4], xb[4];
    #pragma unroll
    for (int p = 0; p < 4; ++p) {
        wb[p] = *reinterpret_cast<const float4*>(wptr + p*16);
        xb[p] = *reinterpret_cast<const float4*>(xptr + p*64);
    }
    for (int kk = 0; kk < KLEN - 4; kk += 4) {
        #pragma unroll
        for (int p = 0; p < 4; ++p) {
            float4 w4 = wb[p], x4 = xb[p];
            wb[p] = *reinterpret_cast<const float4*>(wptr + (kk+4+p)*16);
            xb[p] = *reinterpret_cast<const float4*>(xptr + (kk+4+p)*64);
            float wv[4] = {w4.x, w4.y, w4.z, w4.w};
            float xv[4] = {x4.x, x4.y, x4.z, x4.w};
            #pragma unroll
            for (int i=0;i<4;++i)
                #pragma unroll
                for (int j=0;j<4;++j)
                    acc[i][j] = fmaf(wv[i], xv[j], acc[i][j]);
        }
    }
    #pragma unroll
    for (int p = 0; p < 4; ++p) {
        float wv[4] = {wb[p].x, wb[p].y, wb[p].z, wb[p].w};
        float xv[4] = {xb[p].x, xb[p].y, xb[p].z, xb[p].w};
        #pragma unroll
        for (int i=0;i<4;++i)
            #pragma unroll
            for (int j=0;j<4;++j)
                acc[i][j] = fmaf(wv[i], xv[j], acc[i][j]);
    }

    #pragma unroll
    for (int i = 0; i < 4; ++i) {
        float4 v = make_float4(acc[i][0], acc[i][1], acc[i][2], acc[i][3]);
        *reinterpret_cast<float4*>(&gpart[ks][rg*4 + i][cg*4]) = v;
    }
    __syncthreads();
    if (tid < 200) {
        int ci = tid & 3, b = tid >> 2;
        const float* bp = bsumP + blk*16;
        float s0 = bp[ci], s1 = bp[4+ci], s2 = bp[8+ci], s3 = bp[12+ci];
        #pragma unroll
        for (int p = 0; p < 8; ++p) {
            s0 += gpart[p][ci][b];    s1 += gpart[p][4+ci][b];
            s2 += gpart[p][8+ci][b];  s3 += gpart[p][12+ci][b];
        }
        int col = 4*blk + ci;
        float cold = cT[(size_t)col*64 + b];
        float c = sigm(s1)*cold + sigm(s0)*tanhf(s2);
        float h = sigm(s3)*tanhf(c);
        cT[(size_t)col*64 + b] = c;
        hTnext[(size_t)col*64 + b] = h;
        outs_t[(size_t)b*1024 + col] = h;
    }
}

// ---------------- weight prep for parity-decomposed deconv ----------------
__global__ __launch_bounds__(256)
void wprep_kernel(const float* __restrict__ w, float* __restrict__ wp,
                  int CIN, int COUT, int KS)
{
    int idx = blockIdx.x*256 + threadIdx.x;
    int total = 4*CIN*COUT*12;
    if (idx >= total) return;
    int slot = idx % 12; int rem = idx / 12;
    int o = rem % COUT; rem /= COUT;
    int c = rem % CIN;  int pp = rem / CIN;
    int py = pp >> 1, px = pp & 1;
    int j = slot >> 2, i = slot & 3;
    int ky = py + 2*j, kx = px + 2*i;
    float v = 0.f;
    if (i < 3 && ky < KS && kx < KS)
        v = w[(((size_t)c*COUT + o)*KS + ky)*KS + kx];
    wp[idx] = v;
}

// ---------------- parity-merged transposed conv, v-split blocks -------------
template<int CIN,int COUT,int HIN,int HOUT,int ACT,int VSPLIT,int ROWP,int TWU,
         int VPER,int TB,int MWAVES,int ISTR,int OSTR>
__global__ __launch_bounds__(256, MWAVES)
void deconv4_kernel(const float* __restrict__ in, const float* __restrict__ wp,
                    const float* __restrict__ bias, float* __restrict__ out)
{
    constexpr int NV = (HOUT + 1) / 2;
    constexpr int NVSEG = (NV + VSPLIT - 1) / VSPLIT;
    constexpr int NVB = (NVSEG + VPER - 1) / VPER;
    constexpr int ROWS_MAX = (NVSEG + 2 < HIN) ? (NVSEG + 2) : HIN;
    constexpr int NR4 = (TWU + 2 + 3) / 4;
    constexpr int RLEN = (TWU == 1) ? 4 : NR4*4;
    static_assert(NVB * COUT * TB <= 256, "tasks must fit one per thread");
    __shared__ __align__(16) float slab[CIN*ROWS_MAX*ROWP];

    int n   = blockIdx.x / VSPLIT;
    int seg = blockIdx.x % VSPLIT;
    int v0 = seg * NVSEG;
    int v1 = (v0 + NVSEG < NV) ? v0 + NVSEG : NV;
    int r0 = (v0 - 2 > 0) ? v0 - 2 : 0;
    int r1m = (v1 - 1 < HIN - 1) ? v1 - 1 : HIN - 1;
    int nrows = r1m - r0 + 1;
    int tid = threadIdx.x;
    const float* inb = in + (size_t)n*CIN*HIN*ISTR;
    const size_t PPSTR = (size_t)CIN*COUT*12;

    for (int e = tid; e < CIN*ROWS_MAX; e += 256) {
        int c = e / ROWS_MAX, ri = e % ROWS_MAX;
        if (ri < nrows) {
            const float* src = inb + ((size_t)c*HIN + r0 + ri)*ISTR;
            float* dst = slab + (c*ROWS_MAX + ri)*ROWP;
            dst[0] = 0.f; dst[1] = 0.f;
            #pragma unroll
            for (int x2 = HIN+2; x2 < ROWP; ++x2) dst[x2] = 0.f;
            for (int x2 = 0; x2 < HIN; ++x2) dst[2+x2] = src[x2];
        }
    }
    __syncthreads();

    int task = tid;
    int vi = task % NVB; int rem = task / NVB;
    int o = rem % COUT;  int tb = rem / COUT;
    int u0 = tb * TWU;
    bool anyv = false;
    int vg[VPER];
    #pragma unroll
    for (int q = 0; q < VPER; ++q) {
        vg[q] = v0 + vi + q*NVB;
        if (vg[q] < v1) anyv = true;
    }
    if (tb >= TB) anyv = false;

    float acc[VPER][2][2][TWU];
    #pragma unroll
    for (int q=0;q<VPER;++q)
        #pragma unroll
        for (int a=0;a<2;++a)
            #pragma unroll
            for (int b=0;b<2;++b)
                #pragma unroll
                for (int t=0;t<TWU;++t) acc[q][a][b][t] = 0.f;

    if (anyv) {
        const float* wb0 = wp + (size_t)o*12;
        for (int c = 0; c < CIN; ++c) {
            const float* wbase = wb0 + (size_t)c*COUT*12;
            const float* sc = slab + c*(ROWS_MAX*ROWP);
            #pragma unroll
            for (int jj = 0; jj < 3; ++jj) {
                float r[VPER][RLEN];
                #pragma unroll
                for (int q = 0; q < VPER; ++q) {
                    int iy = vg[q] - jj;
                    if (iy >= 0 && iy < HIN) {
                        const float* srow = sc + (iy - r0)*ROWP + u0;
                        if constexpr (TWU == 1) {
                            r[q][0] = srow[0]; r[q][1] = srow[1]; r[q][2] = srow[2];
                        } else {
                            #pragma unroll
                            for (int p4 = 0; p4 < NR4; ++p4) {
                                float4 f = *reinterpret_cast<const float4*>(srow + p4*4);
                                r[q][p4*4]=f.x; r[q][p4*4+1]=f.y; r[q][p4*4+2]=f.z; r[q][p4*4+3]=f.w;
                            }
                        }
                    } else {
                        #pragma unroll
                        for (int p4 = 0; p4 < RLEN; ++p4) r[q][p4] = 0.f;
                    }
                }
                #pragma unroll
                for (int pp = 0; pp < 4; ++pp) {
                    float4 w4 = *reinterpret_cast<const float4*>(wbase + pp*PPSTR + jj*4);
                    int py = pp >> 1, px = pp & 1;
                    #pragma unroll
                    for (int q = 0; q < VPER; ++q)
                        #pragma unroll
                        for (int t = 0; t < TWU; ++t)
                            acc[q][py][px][t] =
                                fmaf(w4.x, r[q][t+2],
                                fmaf(w4.y, r[q][t+1],
                                fmaf(w4.z, r[q][t], acc[q][py][px][t])));
                }
            }
        }
        float bv = bias[o];
        #pragma unroll
        for (int q = 0; q < VPER; ++q) {
            if (vg[q] >= v1) continue;
            #pragma unroll
            for (int py = 0; py < 2; ++py) {
                int y = py + 2*vg[q];
                if (y >= HOUT) continue;
                float* ob = out + (((size_t)n*COUT + o)*HOUT + y)*OSTR;
                #pragma unroll
                for (int t = 0; t < TWU; ++t) {
                    int x0 = 2*(u0+t);
                    if (x0 + 1 < HOUT) {
                        float2 qv;
                        qv.x = act_apply<ACT>(acc[q][py][0][t] + bv);
                        qv.y = act_apply<ACT>(acc[q][py][1][t] + bv);
                        *reinterpret_cast<float2*>(ob + x0) = qv;
                    } else if (x0 < HOUT) {
                        ob[x0] = act_apply<ACT>(acc[q][py][0][t] + bv);
                    }
                }
            }
        }
    }
}

// ---------------- launch ----------------
extern "C" void kernel_launch(void* const* d_in, const int* in_sizes, int n_in,
                              void* d_out, int out_size, void* d_ws, size_t ws_size,
                              hipStream_t stream)
{
    const float* x       = (const float*)d_in[0];
    const float* action  = (const float*)d_in[1];
    const float* h0      = (const float*)d_in[2];
    const float* c0      = (const float*)d_in[3];
    const float* conv1_w = (const float*)d_in[4];  const float* conv1_b = (const float*)d_in[5];
    const float* conv2_w = (const float*)d_in[6];  const float* conv2_b = (const float*)d_in[7];
    const float* conv3_w = (const float*)d_in[8];  const float* conv3_b = (const float*)d_in[9];
    const float* conv4_w = (const float*)d_in[10]; const float* conv4_b = (const float*)d_in[11];
    const float* fc1_w   = (const float*)d_in[12]; const float* fc1_b   = (const float*)d_in[13];
    const float* fc2_w   = (const float*)d_in[14]; const float* fc2_b   = (const float*)d_in[15];
    const float* w_ih    = (const float*)d_in[16]; const float* w_hh    = (const float*)d_in[17];
    const float* b_ih    = (const float*)d_in[18]; const float* b_hh    = (const float*)d_in[19];
    const float* fcsd_w  = (const float*)d_in[20]; const float* fcsd_b  = (const float*)d_in[21];
    const float* d1_w    = (const float*)d_in[22]; const float* d1_b    = (const float*)d_in[23];
    const float* d2_w    = (const float*)d_in[24]; const float* d2_b    = (const float*)d_in[25];
    const float* d3_w    = (const float*)d_in[26]; const float* d3_b    = (const float*)d_in[27];
    const float* d4_w    = (const float*)d_in[28]; const float* d4_b    = (const float*)d_in[29];
    const float* fc5_w   = (const float*)d_in[30]; const float* fc5_b   = (const float*)d_in[31];
    float* out = (float*)d_out;
    float* ws  = (float*)d_ws;

    // workspace layout (floats)
    float* a1    = ws;                  // 1,537,600  [50,32,31,31]
    float* a2    = a1 + 1537600;        //   627,200  [50,64,14,14]
    float* a3    = a2 + 627200;         //   230,400  [50,128,6,6]
    float* flat  = a3 + 230400;         //    51,200  [50,1024]
    float* z     = flat + 51200;        //    25,600  [50,512]
    float* fc2o  = z + 25600;           //    51,200  [50,1024]
    float* outs  = fc2o + 51200;        //   870,400  [17,50,1024]
    float* hd    = outs + 870400;       //   870,400  [850,1024]
    float* wp2   = hd + 870400;         //   393,216
    float* wp3   = wp2 + 393216;        //    98,304
    float* wp4   = wp3 + 98304;         //     1,536
    float* y1    = wp4 + 1536;          //  2,720,000  [850,128,5,5]
    float* y2    = y1 + 2720000;        //  9,193,600  [850,64,13,13]
    float* y3    = y2 + 9193600;        // 24,480,000  [850,32,30,30]
    float* xx0T  = y3 + 24480000;       //   131,072  [2048][64]
    float* hTbuf = xx0T + 131072;       //   131,072  ping-pong [2][1024][64]
    float* cT    = hTbuf + 131072;      //    65,536  [1024][64]
    float* bsumP = cT + 65536;          //     4,096
    // aliased into decoder buffers (dead until after the LSTM):
    float* wpack  = y2;                 //  4,194,304  [256][1024][16]
    float* wpack0 = y3;                 //  8,388,608  [256][2048][16]

    const int B = 50;

    // deconv weight prep
    wprep_kernel<<<(4*128*64*12+255)/256, 256, 0, stream>>>(d2_w, wp2, 128, 64, 5);
    wprep_kernel<<<(4*64*32*12+255)/256, 256, 0, stream>>>(d3_w, wp3, 64, 32, 6);
    wprep_kernel<<<(4*32*1*12+255)/256, 256, 0, stream>>>(d4_w, wp4, 32, 1, 6);

    // LSTM weight packs (per-block contiguous) + packed bias
    wpack_kernel<<<dim3(256, 16), 256, 0, stream>>>(w_ih, w_hh, wpack, 0);
    wpack_kernel<<<dim3(256, 32), 256, 0, stream>>>(w_ih, w_hh, wpack0, 1);
    bsum_pack_kernel<<<16, 256, 0, stream>>>(b_ih, b_hh, bsumP);

    // encoder
    conv_enc_kernel<1,32><<<(B*32*31*31+255)/256, 256, 0, stream>>>(x, conv1_w, conv1_b, a1, B, 64, 31);
    conv_enc_kernel<32,64><<<(B*64*14*14+255)/256, 256, 0, stream>>>(a1, conv2_w, conv2_b, a2, B, 31, 14);
    conv_enc_kernel<64,128><<<(B*128*6*6+255)/256, 256, 0, stream>>>(a2, conv3_w, conv3_b, a3, B, 14, 6);
    conv_enc_kernel<128,256><<<(B*256*2*2+255)/256, 256, 0, stream>>>(a3, conv4_w, conv4_b, flat, B, 6, 2);

    // fc1 -> z[:, :482]; action -> z[:, 482:512]; reward head
    {
        dim3 grid((482+63)/64, (B+31)/32, 1);
        gemm_kernel<32,64,32,true,0><<<grid, 128, 0, stream>>>(flat, fc1_w, fc1_b, z, B, 482, 1024, 1024, 512, 1, 0);
    }
    concat_action_kernel<<<(1500+63)/64, 64, 0, stream>>>(action, z);
    reward_kernel<<<1, 64, 0, stream>>>(z, fc5_w, fc5_b, out + (size_t)850*4096);

    // fc2 (leaky relu)
    {
        dim3 grid((1024+63)/64, (B+31)/32, 1);
        gemm_kernel<32,64,32,true,2><<<grid, 128, 0, stream>>>(z, fc2_w, fc2_b, fc2o, B, 1024, 512, 512, 1024, 1, 0);
    }

    // LSTM: stage xx0T = [fc2o^T ; h0^T], cT = c0^T; 17 per-step dispatches
    transpose_bt_kernel<<<(65536+255)/256, 256, 0, stream>>>(fc2o, xx0T);
    transpose_bt_kernel<<<(65536+255)/256, 256, 0, stream>>>(h0, xx0T + 65536);
    transpose_bt_kernel<<<(65536+255)/256, 256, 0, stream>>>(c0, cT);
    lstm_step_kernel<1><<<256, 512, 0, stream>>>(xx0T, wpack0, bsumP, cT,
                                                 hTbuf + 65536, outs);
    for (int t = 1; t < 17; ++t) {
        lstm_step_kernel<0><<<256, 512, 0, stream>>>(hTbuf + (size_t)(t & 1)*65536,
                                                     wpack, bsumP, cT,
                                                     hTbuf + (size_t)((t + 1) & 1)*65536,
                                                     outs + (size_t)t*51200);
    }

    // fcsd: hd = leaky(outs @ fcsd_w^T + fcsd_b)   [850,1024]
    {
        dim3 grid((1024+63)/64, (850+63)/64, 1);
        gemm_kernel<64,64,32,true,2><<<grid, 256, 0, stream>>>(outs, fcsd_w, fcsd_b, hd, 850, 1024, 1024, 1024, 1024, 1, 0);
    }
    // d1: 1x1 spatial input -> pure GEMM [850,1024]x[1024,3200], tanh
    // (overwrites y1; y2/y3 aliases of wpack/wpack0 are dead after the LSTM)
    {
        dim3 grid((3200+63)/64, (850+63)/64, 1);
        gemm_kernel<64,64,32,false,1><<<grid, 256, 0, stream>>>(hd, d1_w, d1_b, y1, 850, 3200, 1024, 1024, 3200, 25, 0);
    }

    // d2/d3/d4: round-4 best configs (unpadded strides)
    deconv4_kernel<128,64,5,13,1, 1,12,7,2,1,3, 5,13><<<850, 256, 0, stream>>>(y1, wp2, d2_b, y2);
    deconv4_kernel<64,32,13,30,1, 2,20,15,1,1,3, 13,30><<<1700, 256, 0, stream>>>(y2, wp3, d3_b, y3);
    deconv4_kernel<32,1,30,64,0, 4,36,1,1,32,3, 30,64><<<3400, 256, 0, stream>>>(y3, wp4, d4_b, out);

    (void)in_sizes; (void)n_in; (void)out_size; (void)ws_size;
}